// Round 11
// baseline (291.039 us; speedup 1.0000x reference)
//
#include <hip/hip_runtime.h>
#include <math.h>
#include <stdint.h>

#define L_  1024
#define B_  2
#define D_  1024
#define H_  16
#define DH_ 64
#define M_  1024
#define T_  2048
#define SCALE_ 0.125f
#define SCALE2_ 0.18033688f   // 0.125 * log2(e)

typedef unsigned short ushort;
typedef short bf16x8 __attribute__((ext_vector_type(8)));
typedef float f32x4 __attribute__((ext_vector_type(4)));
typedef unsigned short u16x4v __attribute__((ext_vector_type(4)));
typedef unsigned short u16x8v __attribute__((ext_vector_type(8)));

#define MFMA16(a,b,c) __builtin_amdgcn_mfma_f32_16x16x32_bf16(a,b,c,0,0,0)

#if __has_builtin(__builtin_amdgcn_exp2f)
#define EXP2(x) __builtin_amdgcn_exp2f(x)
#else
#define EXP2(x) exp2f(x)
#endif

static __device__ __forceinline__ ushort f2bf(float x) {
    uint32_t u = __float_as_uint(x);
    uint32_t r = (u + 0x7FFFu + ((u >> 16) & 1u)) >> 16;
    return (ushort)r;
}
// fast round-half-up (hot path only; <=0.5 ULP bias, fine vs 0.0988 threshold)
static __device__ __forceinline__ ushort f2bf_fast(float x) {
    return (ushort)((__float_as_uint(x) + 0x8000u) >> 16);
}
static __device__ __forceinline__ float bf2f(ushort h) {
    return __uint_as_float(((uint32_t)h) << 16);
}
// async global->LDS, 16B per lane; LDS dest = wave-uniform base + lane*16
static __device__ __forceinline__ void gl_lds16(const ushort* g, ushort* l) {
    __builtin_amdgcn_global_load_lds(
        (const __attribute__((address_space(1))) void*)g,
        (__attribute__((address_space(3))) void*)l, 16, 0, 0);
}

// slice tables: grp g has nc=17+g chunks split into ns=ceil(nc/5) slices.
// 85 slices per bh plane -> grid 32*85 = 2720, every slice <=5 chunks.
static __device__ const unsigned char GRP_OF[85] = {
 0,0,0,0, 1,1,1,1, 2,2,2,2, 3,3,3,3,
 4,4,4,4,4, 5,5,5,5,5, 6,6,6,6,6, 7,7,7,7,7, 8,8,8,8,8,
 9,9,9,9,9,9, 10,10,10,10,10,10, 11,11,11,11,11,11,
 12,12,12,12,12,12, 13,13,13,13,13,13,
 14,14,14,14,14,14,14, 15,15,15,15,15,15,15};
static __device__ const unsigned char SLC_OF[85] = {
 0,1,2,3, 0,1,2,3, 0,1,2,3, 0,1,2,3,
 0,1,2,3,4, 0,1,2,3,4, 0,1,2,3,4, 0,1,2,3,4, 0,1,2,3,4,
 0,1,2,3,4,5, 0,1,2,3,4,5, 0,1,2,3,4,5,
 0,1,2,3,4,5, 0,1,2,3,4,5,
 0,1,2,3,4,5,6, 0,1,2,3,4,5,6};
static __device__ const unsigned char NS_OF[16] = {4,4,4,4,5,5,5,5,5,6,6,6,6,6,7,7};

// ---------------------------------------------------------------------------
// Fused prep: fp32->bf16 converts (blocks 0..4095), weight transposes
// (4096..9215), lpart zero-fill (9216..9247).
// ---------------------------------------------------------------------------
__global__ __launch_bounds__(256) void prep(
    const float* __restrict__ memory, const float* __restrict__ x,
    const float* __restrict__ pos_emb,
    const float* __restrict__ Wq, const float* __restrict__ Wkv,
    const float* __restrict__ Wrel, const float* __restrict__ Wo,
    ushort* __restrict__ cb, ushort* __restrict__ pb,
    ushort* __restrict__ Wqt, ushort* __restrict__ Wkvt,
    ushort* __restrict__ Wrelt, ushort* __restrict__ Wot,
    float* __restrict__ lpart)
{
    __shared__ float t[32][33];
    int tid = threadIdx.x;
    if (blockIdx.x >= 9216) {
        int i = ((blockIdx.x - 9216) * 256 + tid) * 4;
        *(float4*)(lpart + i) = (float4){0.f, 0.f, 0.f, 0.f};
        return;
    }
    if (blockIdx.x < 4096) {
        int idx = (blockIdx.x * 256 + tid) * 8;
        const float* s;
        ushort* d;
        if (idx < 2097152)      { s = memory + idx;              d = cb + idx; }
        else if (idx < 4194304) { s = x + (idx - 2097152);       d = cb + idx; }
        else                    { s = pos_emb + (idx - 4194304); d = pb + (idx - 4194304); }
        float4 a = *(const float4*)(s);
        float4 b = *(const float4*)(s + 4);
        u16x8v o;
        o[0] = f2bf(a.x); o[1] = f2bf(a.y); o[2] = f2bf(a.z); o[3] = f2bf(a.w);
        o[4] = f2bf(b.x); o[5] = f2bf(b.y); o[6] = f2bf(b.z); o[7] = f2bf(b.w);
        *(u16x8v*)d = o;
        return;
    }
    int tb = blockIdx.x - 4096;
    const float* src; ushort* dst; int N;
    if (tb < 1024)      { src = Wq;   dst = Wqt;   N = 1024; }
    else if (tb < 3072) { src = Wkv;  dst = Wkvt;  N = 2048; tb -= 1024; }
    else if (tb < 4096) { src = Wrel; dst = Wrelt; N = 1024; tb -= 3072; }
    else                { src = Wo;   dst = Wot;   N = 1024; tb -= 4096; }
    int k0 = (tb & 31) * 32, n0 = (tb >> 5) * 32;
    int r = tid >> 3, c4 = (tid & 7) * 4;
    float4 v = *(const float4*)(src + (size_t)(k0 + r) * N + n0 + c4);
    t[r][c4 + 0] = v.x; t[r][c4 + 1] = v.y; t[r][c4 + 2] = v.z; t[r][c4 + 3] = v.w;
    __syncthreads();
    u16x4v o;
    o[0] = f2bf(t[c4 + 0][r]); o[1] = f2bf(t[c4 + 1][r]);
    o[2] = f2bf(t[c4 + 2][r]); o[3] = f2bf(t[c4 + 3][r]);
    *(u16x4v*)(dst + (size_t)(n0 + r) * 1024 + k0 + c4) = o;
}

// ---------------------------------------------------------------------------
// Single-launch projections, 256x256 tiles, 512 threads (8 waves, 2x4 grid,
// 128x64 output per wave). Triple-buffered BK=32 staging, 2-deep prefetch,
// counted vmcnt(4), literal buffer indices. Vectorized VtB epilogue (16B
// u16x8v stores along t'). Grid 224 blocks.
// ---------------------------------------------------------------------------
__global__ __launch_bounds__(512) void proj_all(
    const ushort* __restrict__ cb, const ushort* __restrict__ pb,
    const ushort* __restrict__ Wqt, const ushort* __restrict__ Wkvt,
    const ushort* __restrict__ Wrelt,
    const float* __restrict__ bu, const float* __restrict__ bv,
    ushort* __restrict__ quB, ushort* __restrict__ qvB,
    ushort* __restrict__ kbB, ushort* __restrict__ VtB,
    ushort* __restrict__ rbB)
{
    __shared__ ushort Al[3][256 * 32];    // 3 x 16 KB
    __shared__ ushort Bl[3][256 * 32];    // 3 x 16 KB  (total 96 KB)
    int lin = blockIdx.x;
    int omode, M0, N0;
    const ushort *A, *Wt;
    if (lin < 32) {
        omode = 0; A = cb + 2097152; Wt = Wqt;
        M0 = (lin & 7) * 256; N0 = (lin >> 3) * 256;
    } else if (lin < 160) {
        omode = 1; A = cb; Wt = Wkvt;
        int l2 = lin - 32;
        M0 = (l2 & 15) * 256; N0 = (l2 >> 4) * 256;
    } else {
        omode = 2; A = pb; Wt = Wrelt;
        int l2 = lin - 160;
        M0 = (l2 & 15) * 256; N0 = (l2 >> 4) * 256;
    }
    int tid = threadIdx.x;
    int wid = tid >> 6, lane = tid & 63, quad = lane >> 4, jl = lane & 15;
    int wr = wid >> 2, wc = wid & 3;      // 2 x 4 wave grid
    int srow = lane >> 2;                 // row within 16-row chunk

    f32x4 acc[8][4];
    #pragma unroll
    for (int i = 0; i < 8; ++i)
        #pragma unroll
        for (int j = 0; j < 4; ++j) acc[i][j] = (f32x4){0.f, 0.f, 0.f, 0.f};

    auto stage = [&](int b_, int k0) {
        #pragma unroll
        for (int c = 0; c < 2; ++c) {
            int chunk = wid * 2 + c;                    // 0..15
            int r  = chunk * 16 + srow;                 // tile row 0..255
            int su = ((lane & 3) - (r >> 1)) & 3;       // source 16B unit
            gl_lds16(A  + (size_t)(M0 + r) * 1024 + k0 + su * 8,
                     &Al[b_][chunk * 512]);
            gl_lds16(Wt + (size_t)(N0 + r) * 1024 + k0 + su * 8,
                     &Bl[b_][chunk * 512]);
        }
        __builtin_amdgcn_sched_barrier(0);
    };

#define PROJ_STEP(IDX, BUF, SBUF, WAITN)                                    \
    {                                                                       \
        asm volatile("s_waitcnt vmcnt(" #WAITN ")" ::: "memory");           \
        __builtin_amdgcn_sched_barrier(0);                                  \
        __builtin_amdgcn_s_barrier();                                       \
        if ((IDX) + 2 < 32) stage((SBUF), ((IDX) + 2) * 32);                \
        bf16x8 af[8], bfr[4];                                               \
        _Pragma("unroll")                                                   \
        for (int mt = 0; mt < 8; ++mt) {                                    \
            int ra = wr * 128 + mt * 16 + jl;                               \
            int u  = (quad + (ra >> 1)) & 3;                                \
            af[mt] = *(const bf16x8*)&Al[(BUF)][ra * 32 + u * 8];           \
        }                                                                   \
        _Pragma("unroll")                                                   \
        for (int nt = 0; nt < 4; ++nt) {                                    \
            int rb_ = wc * 64 + nt * 16 + jl;                               \
            int u   = (quad + (rb_ >> 1)) & 3;                              \
            bfr[nt] = *(const bf16x8*)&Bl[(BUF)][rb_ * 32 + u * 8];         \
        }                                                                   \
        _Pragma("unroll")                                                   \
        for (int mt = 0; mt < 8; ++mt)                                      \
            _Pragma("unroll")                                               \
            for (int nt = 0; nt < 4; ++nt)                                  \
                acc[mt][nt] = MFMA16(af[mt], bfr[nt], acc[mt][nt]);         \
    }

    stage(0, 0);
    stage(1, 32);

    #pragma unroll 1
    for (int i3 = 0; i3 < 30; i3 += 3) {
        PROJ_STEP(i3 + 0, 0, 2, 4);
        PROJ_STEP(i3 + 1, 1, 0, 4);
        PROJ_STEP(i3 + 2, 2, 1, 4);
    }
    PROJ_STEP(30, 0, 2, 4);   // i+2=32: no stage issued
    PROJ_STEP(31, 1, 0, 0);   // final drain
#undef PROJ_STEP

    if (omode == 0) {
        #pragma unroll
        for (int mt = 0; mt < 8; ++mt)
            #pragma unroll
            for (int nt = 0; nt < 4; ++nt)
                #pragma unroll
                for (int r = 0; r < 4; ++r) {
                    int gm = M0 + wr * 128 + mt * 16 + quad * 4 + r;
                    int gn = N0 + wc * 64 + nt * 16 + jl;
                    float v = acc[mt][nt][r];
                    int l = gm >> 1, b = gm & 1;
                    int h = gn >> 6, d = gn & 63;
                    size_t o = ((size_t)((b << 4) | h) * 1024 + l) * 64 + d;
                    quB[o] = f2bf(v + bu[gn]);
                    qvB[o] = f2bf(v + bv[gn]);
                }
    } else if (omode == 2) {
        #pragma unroll
        for (int mt = 0; mt < 8; ++mt)
            #pragma unroll
            for (int nt = 0; nt < 4; ++nt)
                #pragma unroll
                for (int r = 0; r < 4; ++r) {
                    int gm = M0 + wr * 128 + mt * 16 + quad * 4 + r;
                    int gn = N0 + wc * 64 + nt * 16 + jl;
                    int t2 = gm >> 1, b = gm & 1;
                    int h = gn >> 6, d = gn & 63;
                    rbB[((size_t)((b << 4) | h) * 2048 + t2) * 64 + d] =
                        f2bf(acc[mt][nt][r]);
                }
    } else if (N0 < 1024) {
        #pragma unroll
        for (int mt = 0; mt < 8; ++mt)
            #pragma unroll
            for (int nt = 0; nt < 4; ++nt)
                #pragma unroll
                for (int r = 0; r < 4; ++r) {
                    int gm = M0 + wr * 128 + mt * 16 + quad * 4 + r;
                    int gn = N0 + wc * 64 + nt * 16 + jl;
                    int t2 = gm >> 1, b = gm & 1;
                    int h = gn >> 6, d = gn & 63;
                    kbB[((size_t)((b << 4) | h) * 2048 + t2) * 64 + d] =
                        f2bf(acc[mt][nt][r]);
                }
    } else {
        // VtB half, vectorized along t' (verified index-by-index)
        #pragma unroll
        for (int nt = 0; nt < 4; ++nt) {
            int nn = (N0 + wc * 64 + nt * 16 + jl) & 1023;
            int h = nn >> 6, d = nn & 63;
            #pragma unroll
            for (int g = 0; g < 2; ++g)
                #pragma unroll
                for (int b = 0; b < 2; ++b) {
                    u16x8v pk;
                    #pragma unroll
                    for (int e = 0; e < 8; ++e)
                        pk[e] = f2bf(acc[2 * (e & 3) + g][nt][b + 2 * (e >> 2)]);
                    size_t tp = (size_t)(M0 >> 1) + wr * 64 + g * 32 + quad * 8;
                    *(u16x8v*)(VtB + ((size_t)((b << 4) | h) * 64 + d) * 2048 + tp) = pk;
                }
        }
    }
}

// ---------------------------------------------------------------------------
// Score kernel: block-cooperative double-buffered LDS staging of K and R via
// global_load_lds; XOR source-swizzle; counted vmcnt(4) + raw s_barrier.
// Output: direct k'-permuted 8B/lane stores.
// ---------------------------------------------------------------------------
__global__ __launch_bounds__(256) void attn_score(
    const ushort* __restrict__ qu, const ushort* __restrict__ qv,
    const ushort* __restrict__ kb, const ushort* __restrict__ rb,
    float* __restrict__ lpart, ushort* __restrict__ AMw)
{
    __shared__ ushort Kl[2][64 * 64];     // 16 KB
    __shared__ ushort Rl[2][128 * 64];    // 32 KB

    int tid = threadIdx.x, wid = tid >> 6, lane = tid & 63;
    int quad = lane >> 4, jl = lane & 15, jx = jl & 7;

    int lin  = blockIdx.x;             // 2720
    int xcd  = lin & 7;
    int rest = lin >> 3;               // 0..339
    int bh   = (xcd << 2) | (rest & 3);
    int sidx = rest >> 2;              // 0..84
    int grp  = GRP_OF[sidx];
    int slc  = SLC_OF[sidx];
    int nc   = 17 + grp;
    int ns   = NS_OF[grp];
    int cb_  = slc * nc / ns;
    int ce_  = (slc + 1) * nc / ns;
    int it   = grp * 4 + wid;
    int i0w  = it * 16;
    int irow = i0w + quad * 4;

    const ushort* kp  = kb + (size_t)bh * 2048 * 64;
    const ushort* rp  = rb + (size_t)bh * 2048 * 64;
    const ushort* qup = qu + (size_t)bh * 1024 * 64;
    const ushort* qvp = qv + (size_t)bh * 1024 * 64;

    bf16x8 quA[2], qvA[2];
    quA[0] = *(const bf16x8*)(qup + (size_t)(i0w + jl) * 64 + quad * 8);
    quA[1] = *(const bf16x8*)(qup + (size_t)(i0w + jl) * 64 + 32 + quad * 8);
    qvA[0] = *(const bf16x8*)(qvp + (size_t)(i0w + jl) * 64 + quad * 8);
    qvA[1] = *(const bf16x8*)(qvp + (size_t)(i0w + jl) * 64 + 32 + quad * 8);

    ushort* prow0 = AMw + ((size_t)irow * 32 + bh) * 2048 + jl * 4;

    int lrow = lane >> 3;                    // 0..7 = row within region
    int scol = ((lane & 7) ^ lrow) * 8;      // source col (elements)

    f32x4 z = (f32x4){0.f, 0.f, 0.f, 0.f};
    float lsum[4] = {0.f, 0.f, 0.f, 0.f};

    auto stage = [&](int b_, int c) {
        int j0n = c * 64;
        int rbase = 960 + j0n - grp * 64;    // always >= 0
        ushort* KB = &Kl[b_][0];
        ushort* RB = &Rl[b_][0];
        #pragma unroll
        for (int q = 0; q < 6; ++q) {
            int rgn = wid * 6 + q;
            if (rgn < 8) {
                int row = rgn * 8 + lrow;
                gl_lds16(kp + (size_t)(j0n + row) * 64 + scol, KB + rgn * 512);
            } else {
                int row = (rgn - 8) * 8 + lrow;
                int rg = rbase + row;
                rg = rg > 2047 ? 2047 : rg;
                gl_lds16(rp + (size_t)rg * 64 + scol, RB + (rgn - 8) * 512);
            }
        }
        __builtin_amdgcn_sched_barrier(0);
    };

    int buf = 0;
    stage(0, cb_);
    asm volatile("s_waitcnt vmcnt(0)" ::: "memory");
    __builtin_amdgcn_sched_barrier(0);
    __builtin_amdgcn_s_barrier();

    for (int c = cb_; c < ce_; ++c) {
        if (c + 1 < ce_) stage(buf ^ 1, c + 1);   // prefetch next chunk
        int j0 = c * 64;
        int d0 = 1008 + j0 - i0w;
        bool interior = (j0 + 63 <= i0w + M_) && (d0 + 79 <= 2047);
        const ushort* KB = &Kl[buf][0];
        const ushort* RB = &Rl[buf][0];
        f32x4 ac[4];
        #pragma unroll
        for (int su = 0; su < 4; ++su) {
            int row = su * 16 + jl;
            int s0 = (quad ^ jx) * 8;
            bf16x8 k0v = *(const bf16x8*)&KB[row * 64 + s0];
            bf16x8 k1v = *(const bf16x8*)&KB[row * 64 + (s0 ^ 32)];
            f32x4 t = MFMA16(quA[0], k0v, z);
            ac[su] = MFMA16(quA[1], k1v, t);
        }
        int ob = 48 - wid * 16 + jl;
        f32x4 bt[5];
        #pragma unroll
        for (int nt = 0; nt < 5; ++nt) {
            int o = ob + nt * 16;               // 0..127
            int s0 = (quad ^ jx) * 8;
            bf16x8 r0 = *(const bf16x8*)&RB[o * 64 + s0];
            bf16x8 r1 = *(const bf16x8*)&RB[o * 64 + (s0 ^ 32)];
            f32x4 t = MFMA16(qvA[0], r0, z);
            bt[nt] = MFMA16(qvA[1], r1, t);
        }
        float bs[4][5];
        #pragma unroll
        for (int r = 0; r < 4; ++r) {
            int ii = quad * 4 + r;
            int src = (quad << 4) | ((jl + 15 - ii) & 15);
            #pragma unroll
            for (int nt = 0; nt < 5; ++nt) bs[r][nt] = __shfl(bt[nt][r], src);
        }
        if (interior) {
            #pragma unroll
            for (int r = 0; r < 4; ++r) {
                int ii = quad * 4 + r;
                bool hi = (jl > ii);
                u16x4v ps;
                #pragma unroll
                for (int su = 0; su < 4; ++su) {
                    float bd = hi ? bs[r][su + 1] : bs[r][su];
                    float p = EXP2(fminf((ac[su][r] + bd) * SCALE2_, 86.f));
                    lsum[r] += p;
                    ps[su] = f2bf_fast(p);
                }
                *(u16x4v*)(prow0 + (size_t)r * 65536 + j0) = ps;
            }
        } else {
            #pragma unroll
            for (int r = 0; r < 4; ++r) {
                int ii = quad * 4 + r;
                bool hi = (jl > ii);
                u16x4v ps;
                #pragma unroll
                for (int su = 0; su < 4; ++su) {
                    float bd = hi ? bs[r][su + 1] : bs[r][su];
                    float sv = (ac[su][r] + bd) * SCALE2_;
                    int j = j0 + su * 16 + jl;
                    float p = (j <= irow + r + M_) ? EXP2(fminf(sv, 86.f)) : 0.f;
                    lsum[r] += p;
                    ps[su] = f2bf_fast(p);
                }
                *(u16x4v*)(prow0 + (size_t)r * 65536 + j0) = ps;
            }
        }
        asm volatile("s_waitcnt vmcnt(4)" ::: "memory");
        __builtin_amdgcn_sched_barrier(0);
        __builtin_amdgcn_s_barrier();
        buf ^= 1;
    }

    #pragma unroll
    for (int r = 0; r < 4; ++r) {
        #pragma unroll
        for (int off = 1; off < 16; off <<= 1) lsum[r] += __shfl_xor(lsum[r], off);
        if (jl == 0) atomicAdd(&lpart[(size_t)bh * 1024 + irow + r], lsum[r]);
    }
}

// ---------------------------------------------------------------------------
// PV GEMM v2: 256 blocks = 32 bh x 8 supertiles of 128 P-rows (2 mt tiles).
// Vt k-slice staged ONCE per block, shared by both sub-tiles -> Vt traffic /2.
// Wave w (of 4) owns 32 rows: mt = st*2 + (w>>1), rows (w&1)*32 within mt.
// Per-wave kend guard is wave-uniform; barriers outside -> no divergence.
// ---------------------------------------------------------------------------
__global__ __launch_bounds__(256) void pv_gemm(
    const ushort* __restrict__ P, const ushort* __restrict__ Vt,
    const float* __restrict__ lpart,
    ushort* __restrict__ OvecB, float* __restrict__ linvs)
{
    __shared__ ushort Al[128][40];
    __shared__ ushort Bl[64][40];
    int tid = threadIdx.x;
    int lin  = blockIdx.x;             // 256
    int xcd  = lin & 7;
    int rest = lin >> 3;               // 0..31
    int bh   = (xcd << 2) | (rest & 3);
    int st   = rest >> 2;              // 0..7
    int M0   = st * 128;
    int wid = tid >> 6, lane = tid & 63, quad = lane >> 4, jl = lane & 15;
    int mt   = st * 2 + (wid >> 1);
    int m0w  = (wid >> 1) * 64 + (wid & 1) * 32;   // row offset in supertile
    int kend_w   = (17 + mt) * 64;
    int kend_max = (18 + st * 2) * 64;

    const ushort* Bp = Vt + (size_t)bh * 64 * 2048;
    int sr = tid >> 2, sc = (tid & 3) * 8;

    f32x4 acc[2][4];
    #pragma unroll
    for (int i = 0; i < 2; ++i)
        #pragma unroll
        for (int j = 0; j < 4; ++j) acc[i][j] = (f32x4){0.f, 0.f, 0.f, 0.f};

    for (int k0 = 0; k0 < kend_max; k0 += 32) {
        // stage P rows 0..127 (2 passes) and Vt slice 64 x 32 (1 pass)
        *(u16x8v*)&Al[sr][sc] =
            *(const u16x8v*)(P + ((size_t)(M0 + sr) * 32 + bh) * 2048 + k0 + sc);
        *(u16x8v*)&Al[sr + 64][sc] =
            *(const u16x8v*)(P + ((size_t)(M0 + sr + 64) * 32 + bh) * 2048 + k0 + sc);
        *(u16x8v*)&Bl[sr][sc] = *(const u16x8v*)(Bp + (size_t)sr * 2048 + k0 + sc);
        __syncthreads();
        if (k0 < kend_w) {                       // wave-uniform
            bf16x8 a0 = *(const bf16x8*)&Al[m0w + jl][quad * 8];
            bf16x8 a1 = *(const bf16x8*)&Al[m0w + 16 + jl][quad * 8];
            bf16x8 b0 = *(const bf16x8*)&Bl[jl][quad * 8];
            bf16x8 b1 = *(const bf16x8*)&Bl[16 + jl][quad * 8];
            bf16x8 b2 = *(const bf16x8*)&Bl[32 + jl][quad * 8];
            bf16x8 b3 = *(const bf16x8*)&Bl[48 + jl][quad * 8];
            acc[0][0] = MFMA16(a0, b0, acc[0][0]);
            acc[0][1] = MFMA16(a0, b1, acc[0][1]);
            acc[0][2] = MFMA16(a0, b2, acc[0][2]);
            acc[0][3] = MFMA16(a0, b3, acc[0][3]);
            acc[1][0] = MFMA16(a1, b0, acc[1][0]);
            acc[1][1] = MFMA16(a1, b1, acc[1][1]);
            acc[1][2] = MFMA16(a1, b2, acc[1][2]);
            acc[1][3] = MFMA16(a1, b3, acc[1][3]);
        }
        __syncthreads();
    }

    int b = bh >> 4, h = bh & 15;
    #pragma unroll
    for (int ms = 0; ms < 2; ++ms)
        #pragma unroll
        for (int r = 0; r < 4; ++r) {
            int gi = M0 + m0w + 16 * ms + quad * 4 + r;
            float linv = 1.f / lpart[(size_t)bh * 1024 + gi];
            #pragma unroll
            for (int ns = 0; ns < 4; ++ns) {
                int gd = 16 * ns + jl;
                OvecB[(size_t)(gi * 2 + b) * 1024 + h * 64 + gd] =
                    f2bf(acc[ms][ns][r] * linv);
            }
            if (jl == 0)
                linvs[(size_t)gi * 32 + bh] = linv * 0.03125f;
        }
}

// ---------------------------------------------------------------------------
// Fused tail: blocks [0,128) = output projection + residual, 128x128 tiles
// (double-buffered gl_lds16 pipeline, unit swizzle -- round-6 proj skeleton);
// blocks [128,1152) = am_reduce row i = lin-128.
// ---------------------------------------------------------------------------
__global__ __launch_bounds__(256) void tail_fused(
    const ushort* __restrict__ A, const ushort* __restrict__ Wt,
    const float* __restrict__ resid, float* __restrict__ outF,
    const ushort* __restrict__ AMw, const float* __restrict__ linvs,
    float* __restrict__ AM)
{
    __shared__ ushort Al[2][128 * 32];
    __shared__ ushort Bl[2][128 * 32];
    int tid = threadIdx.x;
    int lin = blockIdx.x;
    if (lin >= 128) {
        // ---- am_reduce ----
        __shared__ float lv[32];
        __shared__ float jbuf[2048];
        int i = lin - 128;
        if (tid < 32) lv[tid] = linvs[(size_t)i * 32 + tid];
        __syncthreads();
        int k0 = tid * 8;                  // k' index
        int jmax = i + M_;
        float acc[8];
        #pragma unroll
        for (int e = 0; e < 8; ++e) acc[e] = 0.f;
        if ((k0 & ~63) <= jmax) {          // chunk base <= jmax -> chunk stored
            const ushort* base = AMw + (size_t)i * 65536;
            for (int p = 0; p < 32; ++p) {
                float l = lv[p];
                u16x8v v = *(const u16x8v*)(base + (size_t)p * 2048 + k0);
                #pragma unroll
                for (int e = 0; e < 8; ++e) acc[e] += bf2f(v[e]) * l;
            }
        }
        // un-permute k' -> true j via LDS
        #pragma unroll
        for (int e = 0; e < 8; ++e) {
            int kp = k0 + e;
            int j  = (kp & ~63) | ((kp & 3) << 4) | ((kp >> 2) & 15);
            jbuf[j] = acc[e];
        }
        __syncthreads();
        int j0 = tid * 8;
        float4 o0, o1;
        o0.x = (j0 + 0 <= jmax) ? jbuf[j0 + 0] : 0.f;
        o0.y = (j0 + 1 <= jmax) ? jbuf[j0 + 1] : 0.f;
        o0.z = (j0 + 2 <= jmax) ? jbuf[j0 + 2] : 0.f;
        o0.w = (j0 + 3 <= jmax) ? jbuf[j0 + 3] : 0.f;
        o1.x = (j0 + 4 <= jmax) ? jbuf[j0 + 4] : 0.f;
        o1.y = (j0 + 5 <= jmax) ? jbuf[j0 + 5] : 0.f;
        o1.z = (j0 + 6 <= jmax) ? jbuf[j0 + 6] : 0.f;
        o1.w = (j0 + 7 <= jmax) ? jbuf[j0 + 7] : 0.f;
        *(float4*)(AM + (size_t)i * 2048 + j0) = o0;
        *(float4*)(AM + (size_t)i * 2048 + j0 + 4) = o1;
        return;
    }
    // ---- gemm_o: 128x128 tiles, 16 x 8 grid ----
    int M0 = (lin & 15) * 128, N0 = (lin >> 4) * 128;
    int wid = tid >> 6, lane = tid & 63, quad = lane >> 4, jl = lane & 15;
    int wr = wid >> 1, wc = wid & 1;
    int srow = lane >> 2;

    f32x4 acc[4][4];
    #pragma unroll
    for (int i = 0; i < 4; ++i)
        #pragma unroll
        for (int j = 0; j < 4; ++j) acc[i][j] = (f32x4){0.f, 0.f, 0.f, 0.f};

    auto stage = [&](int b_, int k0) {
        #pragma unroll
        for (int c = 0; c < 2; ++c) {
            int r  = wid * 32 + c * 16 + srow;          // tile row 0..127
            int su = ((lane & 3) - (r >> 1)) & 3;       // source 16B unit
            gl_lds16(A  + (size_t)(M0 + r) * 1024 + k0 + su * 8,
                     &Al[b_][wid * 1024 + c * 512]);
            gl_lds16(Wt + (size_t)(N0 + r) * 1024 + k0 + su * 8,
                     &Bl[b_][wid * 1024 + c * 512]);
        }
        __builtin_amdgcn_sched_barrier(0);
    };

    int buf = 0;
    stage(0, 0);
    asm volatile("s_waitcnt vmcnt(0)" ::: "memory");
    __builtin_amdgcn_sched_barrier(0);
    __builtin_amdgcn_s_barrier();

    for (int k0 = 0; k0 < 1024; k0 += 32) {
        if (k0 + 32 < 1024) stage(buf ^ 1, k0 + 32);   // prefetch next slice
        bf16x8 af[4], bfr[4];
        #pragma unroll
        for (int mt = 0; mt < 4; ++mt) {
            int ra = wr * 64 + mt * 16 + jl;
            int u  = (quad + (ra >> 1)) & 3;
            af[mt] = *(const bf16x8*)&Al[buf][ra * 32 + u * 8];
        }
        #pragma unroll
        for (int nt = 0; nt < 4; ++nt) {
            int rb_ = wc * 64 + nt * 16 + jl;
            int u   = (quad + (rb_ >> 1)) & 3;
            bfr[nt] = *(const bf16x8*)&Bl[buf][rb_ * 32 + u * 8];
        }
        #pragma unroll
        for (int mt = 0; mt < 4; ++mt)
            #pragma unroll
            for (int nt = 0; nt < 4; ++nt)
                acc[mt][nt] = MFMA16(af[mt], bfr[nt], acc[mt][nt]);
        asm volatile("s_waitcnt vmcnt(0)" ::: "memory");
        __builtin_amdgcn_sched_barrier(0);
        __builtin_amdgcn_s_barrier();
        buf ^= 1;
    }

    #pragma unroll
    for (int mt = 0; mt < 4; ++mt)
        #pragma unroll
        for (int nt = 0; nt < 4; ++nt)
            #pragma unroll
            for (int r = 0; r < 4; ++r) {
                int gm = M0 + wr * 64 + mt * 16 + quad * 4 + r;
                int gn = N0 + wc * 64 + nt * 16 + jl;
                outF[(size_t)gm * 1024 + gn] =
                    acc[mt][nt][r] + resid[(size_t)gm * 1024 + gn];
            }
}

// ---------------------------------------------------------------------------
// LayerNorm over D=1024, one block per row
// ---------------------------------------------------------------------------
__global__ __launch_bounds__(256) void ln_kernel(
    const float* __restrict__ hbuf,
    const float* __restrict__ gamma, const float* __restrict__ beta,
    float* __restrict__ out)
{
    __shared__ float rs[4], rss[4];
    int row = blockIdx.x;
    int tid = threadIdx.x;
    const float* hp = hbuf + (size_t)row * 1024;
    float4 h4 = *(const float4*)(hp + (tid << 2));
    float s = h4.x + h4.y + h4.z + h4.w;
    float ss = h4.x * h4.x + h4.y * h4.y + h4.z * h4.z + h4.w * h4.w;
    #pragma unroll
    for (int o = 32; o > 0; o >>= 1) {
        s  += __shfl_down(s, o);
        ss += __shfl_down(ss, o);
    }
    if ((tid & 63) == 0) { rs[tid >> 6] = s; rss[tid >> 6] = ss; }
    __syncthreads();
    float tot  = rs[0] + rs[1] + rs[2] + rs[3];
    float tots = rss[0] + rss[1] + rss[2] + rss[3];
    float mu = tot * (1.f / 1024.f);
    float var = tots * (1.f / 1024.f) - mu * mu;
    float rstd = rsqrtf(var + 1e-5f);
    float4 g4 = *(const float4*)(gamma + (tid << 2));
    float4 b4 = *(const float4*)(beta + (tid << 2));
    float4 o4;
    o4.x = (h4.x - mu) * rstd * g4.x + b4.x;
    o4.y = (h4.y - mu) * rstd * g4.y + b4.y;
    o4.z = (h4.z - mu) * rstd * g4.z + b4.z;
    o4.w = (h4.w - mu) * rstd * g4.w + b4.w;
    *(float4*)(out + (size_t)row * 1024 + (tid << 2)) = o4;
}

extern "C" void kernel_launch(void* const* d_in, const int* in_sizes, int n_in,
                              void* d_out, int out_size, void* d_ws, size_t ws_size,
                              hipStream_t stream) {
    const float* x       = (const float*)d_in[0];
    const float* pos_emb = (const float*)d_in[1];
    const float* memory  = (const float*)d_in[2];
    const float* bu      = (const float*)d_in[3];
    const float* bv      = (const float*)d_in[4];
    const float* Wq      = (const float*)d_in[6];
    const float* Wkv     = (const float*)d_in[7];
    const float* Wrel    = (const float*)d_in[8];
    const float* Wo      = (const float*)d_in[9];
    const float* gamma   = (const float*)d_in[10];
    const float* beta    = (const float*)d_in[11];

    float* out = (float*)d_out;
    float* AM  = out + (size_t)2097152;       // attn_matrix [L][T]

    ushort* cb    = (ushort*)d_ws;            // [4096][1024]
    ushort* pb    = cb    + 4194304;          // [4096][1024]
    ushort* Wqt   = pb    + 4194304;          // [1024][1024]
    ushort* Wkvt  = Wqt   + 1048576;          // [2048][1024]
    ushort* Wrelt = Wkvt  + 2097152;          // [1024][1024]
    ushort* Wot   = Wrelt + 1048576;          // [1024][1024]
    ushort* quB   = Wot   + 1048576;          // [32][1024][64]
    ushort* qvB   = quB   + 2097152;
    ushort* kbB   = qvB   + 2097152;          // [32][2048][64]
    ushort* VtB   = kbB   + 4194304;          // [32][64][2048] (k-permuted cols)
    ushort* rbB   = VtB   + 4194304;          // [32][2048][64]
    ushort* OvecB = rbB   + 4194304;          // [2048][1024]
    float*  hbuf  = (float*)(OvecB + 2097152);// [2048][1024] fp32
    float*  lpart = hbuf  + 2097152;          // [32][1024] fp32
    float*  linvs = lpart + 32768;            // [1024][32] fp32
    ushort* AMw   = (ushort*)(linvs + 32768); // [1024][32][2048] bf16 k-permuted

    dim3 blk(256);
    // fused converts + weight transposes + lpart clear
    prep<<<9248, blk, 0, stream>>>(memory, x, pos_emb, Wq, Wkv, Wrel, Wo,
                                   cb, pb, Wqt, Wkvt, Wrelt, Wot, lpart);
    // all projections: 256^2 tiles, 8 waves, vectorized VtB epilogue
    proj_all<<<224, dim3(512), 0, stream>>>(cb, pb, Wqt, Wkvt, Wrelt, bu, bv,
                                            quB, qvB, kbB, VtB, rbB);
    // scores -> planes (block-coop LDS staging, counted vmcnt, raw barriers)
    attn_score<<<dim3(2720), blk, 0, stream>>>(quB, qvB, kbB, rbB, lpart, AMw);
    // PV: 128-row supertiles sharing Vt slices (Vt traffic /2), grid 256
    pv_gemm<<<dim3(256), blk, 0, stream>>>(AMw, VtB, lpart, OvecB, linvs);
    // fused output projection (128^2 pipelined tiles) + attn_matrix reduction
    tail_fused<<<dim3(1152), blk, 0, stream>>>(OvecB, Wot, x, hbuf,
                                               AMw, linvs, AM);
    // layernorm
    ln_kernel<<<2048, blk, 0, stream>>>(hbuf, gamma, beta, out);
}

// Round 12
// 273.637 us; speedup vs baseline: 1.0636x; 1.0636x over previous
//
#include <hip/hip_runtime.h>
#include <math.h>
#include <stdint.h>

#define L_  1024
#define B_  2
#define D_  1024
#define H_  16
#define DH_ 64
#define M_  1024
#define T_  2048
#define SCALE_ 0.125f
#define SCALE2_ 0.18033688f   // 0.125 * log2(e)

typedef unsigned short ushort;
typedef short bf16x8 __attribute__((ext_vector_type(8)));
typedef float f32x4 __attribute__((ext_vector_type(4)));
typedef unsigned short u16x4v __attribute__((ext_vector_type(4)));
typedef unsigned short u16x8v __attribute__((ext_vector_type(8)));

#define MFMA16(a,b,c) __builtin_amdgcn_mfma_f32_16x16x32_bf16(a,b,c,0,0,0)

#if __has_builtin(__builtin_amdgcn_exp2f)
#define EXP2(x) __builtin_amdgcn_exp2f(x)
#else
#define EXP2(x) exp2f(x)
#endif

static __device__ __forceinline__ ushort f2bf(float x) {
    uint32_t u = __float_as_uint(x);
    uint32_t r = (u + 0x7FFFu + ((u >> 16) & 1u)) >> 16;
    return (ushort)r;
}
// fast round-half-up (hot path only; <=0.5 ULP bias, fine vs 0.0988 threshold)
static __device__ __forceinline__ ushort f2bf_fast(float x) {
    return (ushort)((__float_as_uint(x) + 0x8000u) >> 16);
}
static __device__ __forceinline__ float bf2f(ushort h) {
    return __uint_as_float(((uint32_t)h) << 16);
}
// async global->LDS, 16B per lane; LDS dest = wave-uniform base + lane*16
static __device__ __forceinline__ void gl_lds16(const ushort* g, ushort* l) {
    __builtin_amdgcn_global_load_lds(
        (const __attribute__((address_space(1))) void*)g,
        (__attribute__((address_space(3))) void*)l, 16, 0, 0);
}

// slice tables: grp g has nc=17+g chunks split into ns=ceil(nc/5) slices.
// 85 slices per bh plane -> grid 32*85 = 2720, every slice <=5 chunks.
static __device__ const unsigned char GRP_OF[85] = {
 0,0,0,0, 1,1,1,1, 2,2,2,2, 3,3,3,3,
 4,4,4,4,4, 5,5,5,5,5, 6,6,6,6,6, 7,7,7,7,7, 8,8,8,8,8,
 9,9,9,9,9,9, 10,10,10,10,10,10, 11,11,11,11,11,11,
 12,12,12,12,12,12, 13,13,13,13,13,13,
 14,14,14,14,14,14,14, 15,15,15,15,15,15,15};
static __device__ const unsigned char SLC_OF[85] = {
 0,1,2,3, 0,1,2,3, 0,1,2,3, 0,1,2,3,
 0,1,2,3,4, 0,1,2,3,4, 0,1,2,3,4, 0,1,2,3,4, 0,1,2,3,4,
 0,1,2,3,4,5, 0,1,2,3,4,5, 0,1,2,3,4,5,
 0,1,2,3,4,5, 0,1,2,3,4,5,
 0,1,2,3,4,5,6, 0,1,2,3,4,5,6};
static __device__ const unsigned char NS_OF[16] = {4,4,4,4,5,5,5,5,5,6,6,6,6,6,7,7};

// ---------------------------------------------------------------------------
// Fused prep: fp32->bf16 converts (blocks 0..4095), weight transposes
// (4096..9215), lpart zero-fill (9216..9247).
// ---------------------------------------------------------------------------
__global__ __launch_bounds__(256) void prep(
    const float* __restrict__ memory, const float* __restrict__ x,
    const float* __restrict__ pos_emb,
    const float* __restrict__ Wq, const float* __restrict__ Wkv,
    const float* __restrict__ Wrel, const float* __restrict__ Wo,
    ushort* __restrict__ cb, ushort* __restrict__ pb,
    ushort* __restrict__ Wqt, ushort* __restrict__ Wkvt,
    ushort* __restrict__ Wrelt, ushort* __restrict__ Wot,
    float* __restrict__ lpart)
{
    __shared__ float t[32][33];
    int tid = threadIdx.x;
    if (blockIdx.x >= 9216) {
        int i = ((blockIdx.x - 9216) * 256 + tid) * 4;
        *(float4*)(lpart + i) = (float4){0.f, 0.f, 0.f, 0.f};
        return;
    }
    if (blockIdx.x < 4096) {
        int idx = (blockIdx.x * 256 + tid) * 8;
        const float* s;
        ushort* d;
        if (idx < 2097152)      { s = memory + idx;              d = cb + idx; }
        else if (idx < 4194304) { s = x + (idx - 2097152);       d = cb + idx; }
        else                    { s = pos_emb + (idx - 4194304); d = pb + (idx - 4194304); }
        float4 a = *(const float4*)(s);
        float4 b = *(const float4*)(s + 4);
        u16x8v o;
        o[0] = f2bf(a.x); o[1] = f2bf(a.y); o[2] = f2bf(a.z); o[3] = f2bf(a.w);
        o[4] = f2bf(b.x); o[5] = f2bf(b.y); o[6] = f2bf(b.z); o[7] = f2bf(b.w);
        *(u16x8v*)d = o;
        return;
    }
    int tb = blockIdx.x - 4096;
    const float* src; ushort* dst; int N;
    if (tb < 1024)      { src = Wq;   dst = Wqt;   N = 1024; }
    else if (tb < 3072) { src = Wkv;  dst = Wkvt;  N = 2048; tb -= 1024; }
    else if (tb < 4096) { src = Wrel; dst = Wrelt; N = 1024; tb -= 3072; }
    else                { src = Wo;   dst = Wot;   N = 1024; tb -= 4096; }
    int k0 = (tb & 31) * 32, n0 = (tb >> 5) * 32;
    int r = tid >> 3, c4 = (tid & 7) * 4;
    float4 v = *(const float4*)(src + (size_t)(k0 + r) * N + n0 + c4);
    t[r][c4 + 0] = v.x; t[r][c4 + 1] = v.y; t[r][c4 + 2] = v.z; t[r][c4 + 3] = v.w;
    __syncthreads();
    u16x4v o;
    o[0] = f2bf(t[c4 + 0][r]); o[1] = f2bf(t[c4 + 1][r]);
    o[2] = f2bf(t[c4 + 2][r]); o[3] = f2bf(t[c4 + 3][r]);
    *(u16x4v*)(dst + (size_t)(n0 + r) * 1024 + k0 + c4) = o;
}

// ---------------------------------------------------------------------------
// Single-launch projections, 256x256 tiles, 512 threads (8 waves, 2x4 grid,
// 128x64 output per wave). Triple-buffered BK=32 staging, 2-deep prefetch,
// counted vmcnt(4), literal buffer indices. Vectorized VtB epilogue (16B
// u16x8v stores along t'). Grid 224 blocks.
// ---------------------------------------------------------------------------
__global__ __launch_bounds__(512) void proj_all(
    const ushort* __restrict__ cb, const ushort* __restrict__ pb,
    const ushort* __restrict__ Wqt, const ushort* __restrict__ Wkvt,
    const ushort* __restrict__ Wrelt,
    const float* __restrict__ bu, const float* __restrict__ bv,
    ushort* __restrict__ quB, ushort* __restrict__ qvB,
    ushort* __restrict__ kbB, ushort* __restrict__ VtB,
    ushort* __restrict__ rbB)
{
    __shared__ ushort Al[3][256 * 32];    // 3 x 16 KB
    __shared__ ushort Bl[3][256 * 32];    // 3 x 16 KB  (total 96 KB)
    int lin = blockIdx.x;
    int omode, M0, N0;
    const ushort *A, *Wt;
    if (lin < 32) {
        omode = 0; A = cb + 2097152; Wt = Wqt;
        M0 = (lin & 7) * 256; N0 = (lin >> 3) * 256;
    } else if (lin < 160) {
        omode = 1; A = cb; Wt = Wkvt;
        int l2 = lin - 32;
        M0 = (l2 & 15) * 256; N0 = (l2 >> 4) * 256;
    } else {
        omode = 2; A = pb; Wt = Wrelt;
        int l2 = lin - 160;
        M0 = (l2 & 15) * 256; N0 = (l2 >> 4) * 256;
    }
    int tid = threadIdx.x;
    int wid = tid >> 6, lane = tid & 63, quad = lane >> 4, jl = lane & 15;
    int wr = wid >> 2, wc = wid & 3;      // 2 x 4 wave grid
    int srow = lane >> 2;                 // row within 16-row chunk

    f32x4 acc[8][4];
    #pragma unroll
    for (int i = 0; i < 8; ++i)
        #pragma unroll
        for (int j = 0; j < 4; ++j) acc[i][j] = (f32x4){0.f, 0.f, 0.f, 0.f};

    auto stage = [&](int b_, int k0) {
        #pragma unroll
        for (int c = 0; c < 2; ++c) {
            int chunk = wid * 2 + c;                    // 0..15
            int r  = chunk * 16 + srow;                 // tile row 0..255
            int su = ((lane & 3) - (r >> 1)) & 3;       // source 16B unit
            gl_lds16(A  + (size_t)(M0 + r) * 1024 + k0 + su * 8,
                     &Al[b_][chunk * 512]);
            gl_lds16(Wt + (size_t)(N0 + r) * 1024 + k0 + su * 8,
                     &Bl[b_][chunk * 512]);
        }
        __builtin_amdgcn_sched_barrier(0);
    };

#define PROJ_STEP(IDX, BUF, SBUF, WAITN)                                    \
    {                                                                       \
        asm volatile("s_waitcnt vmcnt(" #WAITN ")" ::: "memory");           \
        __builtin_amdgcn_sched_barrier(0);                                  \
        __builtin_amdgcn_s_barrier();                                       \
        if ((IDX) + 2 < 32) stage((SBUF), ((IDX) + 2) * 32);                \
        bf16x8 af[8], bfr[4];                                               \
        _Pragma("unroll")                                                   \
        for (int mt = 0; mt < 8; ++mt) {                                    \
            int ra = wr * 128 + mt * 16 + jl;                               \
            int u  = (quad + (ra >> 1)) & 3;                                \
            af[mt] = *(const bf16x8*)&Al[(BUF)][ra * 32 + u * 8];           \
        }                                                                   \
        _Pragma("unroll")                                                   \
        for (int nt = 0; nt < 4; ++nt) {                                    \
            int rb_ = wc * 64 + nt * 16 + jl;                               \
            int u   = (quad + (rb_ >> 1)) & 3;                              \
            bfr[nt] = *(const bf16x8*)&Bl[(BUF)][rb_ * 32 + u * 8];         \
        }                                                                   \
        _Pragma("unroll")                                                   \
        for (int mt = 0; mt < 8; ++mt)                                      \
            _Pragma("unroll")                                               \
            for (int nt = 0; nt < 4; ++nt)                                  \
                acc[mt][nt] = MFMA16(af[mt], bfr[nt], acc[mt][nt]);         \
    }

    stage(0, 0);
    stage(1, 32);

    #pragma unroll 1
    for (int i3 = 0; i3 < 30; i3 += 3) {
        PROJ_STEP(i3 + 0, 0, 2, 4);
        PROJ_STEP(i3 + 1, 1, 0, 4);
        PROJ_STEP(i3 + 2, 2, 1, 4);
    }
    PROJ_STEP(30, 0, 2, 4);   // i+2=32: no stage issued
    PROJ_STEP(31, 1, 0, 0);   // final drain
#undef PROJ_STEP

    if (omode == 0) {
        #pragma unroll
        for (int mt = 0; mt < 8; ++mt)
            #pragma unroll
            for (int nt = 0; nt < 4; ++nt)
                #pragma unroll
                for (int r = 0; r < 4; ++r) {
                    int gm = M0 + wr * 128 + mt * 16 + quad * 4 + r;
                    int gn = N0 + wc * 64 + nt * 16 + jl;
                    float v = acc[mt][nt][r];
                    int l = gm >> 1, b = gm & 1;
                    int h = gn >> 6, d = gn & 63;
                    size_t o = ((size_t)((b << 4) | h) * 1024 + l) * 64 + d;
                    quB[o] = f2bf(v + bu[gn]);
                    qvB[o] = f2bf(v + bv[gn]);
                }
    } else if (omode == 2) {
        #pragma unroll
        for (int mt = 0; mt < 8; ++mt)
            #pragma unroll
            for (int nt = 0; nt < 4; ++nt)
                #pragma unroll
                for (int r = 0; r < 4; ++r) {
                    int gm = M0 + wr * 128 + mt * 16 + quad * 4 + r;
                    int gn = N0 + wc * 64 + nt * 16 + jl;
                    int t2 = gm >> 1, b = gm & 1;
                    int h = gn >> 6, d = gn & 63;
                    rbB[((size_t)((b << 4) | h) * 2048 + t2) * 64 + d] =
                        f2bf(acc[mt][nt][r]);
                }
    } else if (N0 < 1024) {
        #pragma unroll
        for (int mt = 0; mt < 8; ++mt)
            #pragma unroll
            for (int nt = 0; nt < 4; ++nt)
                #pragma unroll
                for (int r = 0; r < 4; ++r) {
                    int gm = M0 + wr * 128 + mt * 16 + quad * 4 + r;
                    int gn = N0 + wc * 64 + nt * 16 + jl;
                    int t2 = gm >> 1, b = gm & 1;
                    int h = gn >> 6, d = gn & 63;
                    kbB[((size_t)((b << 4) | h) * 2048 + t2) * 64 + d] =
                        f2bf(acc[mt][nt][r]);
                }
    } else {
        // VtB half, vectorized along t' (verified index-by-index)
        #pragma unroll
        for (int nt = 0; nt < 4; ++nt) {
            int nn = (N0 + wc * 64 + nt * 16 + jl) & 1023;
            int h = nn >> 6, d = nn & 63;
            #pragma unroll
            for (int g = 0; g < 2; ++g)
                #pragma unroll
                for (int b = 0; b < 2; ++b) {
                    u16x8v pk;
                    #pragma unroll
                    for (int e = 0; e < 8; ++e)
                        pk[e] = f2bf(acc[2 * (e & 3) + g][nt][b + 2 * (e >> 2)]);
                    size_t tp = (size_t)(M0 >> 1) + wr * 64 + g * 32 + quad * 8;
                    *(u16x8v*)(VtB + ((size_t)((b << 4) | h) * 64 + d) * 2048 + tp) = pk;
                }
        }
    }
}

// ---------------------------------------------------------------------------
// Score kernel: block-cooperative double-buffered LDS staging of K and R via
// global_load_lds; XOR source-swizzle; counted vmcnt(4) + raw s_barrier.
// Output: direct k'-permuted 8B/lane stores.
// ---------------------------------------------------------------------------
__global__ __launch_bounds__(256) void attn_score(
    const ushort* __restrict__ qu, const ushort* __restrict__ qv,
    const ushort* __restrict__ kb, const ushort* __restrict__ rb,
    float* __restrict__ lpart, ushort* __restrict__ AMw)
{
    __shared__ ushort Kl[2][64 * 64];     // 16 KB
    __shared__ ushort Rl[2][128 * 64];    // 32 KB

    int tid = threadIdx.x, wid = tid >> 6, lane = tid & 63;
    int quad = lane >> 4, jl = lane & 15, jx = jl & 7;

    int lin  = blockIdx.x;             // 2720
    int xcd  = lin & 7;
    int rest = lin >> 3;               // 0..339
    int bh   = (xcd << 2) | (rest & 3);
    int sidx = rest >> 2;              // 0..84
    int grp  = GRP_OF[sidx];
    int slc  = SLC_OF[sidx];
    int nc   = 17 + grp;
    int ns   = NS_OF[grp];
    int cb_  = slc * nc / ns;
    int ce_  = (slc + 1) * nc / ns;
    int it   = grp * 4 + wid;
    int i0w  = it * 16;
    int irow = i0w + quad * 4;

    const ushort* kp  = kb + (size_t)bh * 2048 * 64;
    const ushort* rp  = rb + (size_t)bh * 2048 * 64;
    const ushort* qup = qu + (size_t)bh * 1024 * 64;
    const ushort* qvp = qv + (size_t)bh * 1024 * 64;

    bf16x8 quA[2], qvA[2];
    quA[0] = *(const bf16x8*)(qup + (size_t)(i0w + jl) * 64 + quad * 8);
    quA[1] = *(const bf16x8*)(qup + (size_t)(i0w + jl) * 64 + 32 + quad * 8);
    qvA[0] = *(const bf16x8*)(qvp + (size_t)(i0w + jl) * 64 + quad * 8);
    qvA[1] = *(const bf16x8*)(qvp + (size_t)(i0w + jl) * 64 + 32 + quad * 8);

    ushort* prow0 = AMw + ((size_t)irow * 32 + bh) * 2048 + jl * 4;

    int lrow = lane >> 3;                    // 0..7 = row within region
    int scol = ((lane & 7) ^ lrow) * 8;      // source col (elements)

    f32x4 z = (f32x4){0.f, 0.f, 0.f, 0.f};
    float lsum[4] = {0.f, 0.f, 0.f, 0.f};

    auto stage = [&](int b_, int c) {
        int j0n = c * 64;
        int rbase = 960 + j0n - grp * 64;    // always >= 0
        ushort* KB = &Kl[b_][0];
        ushort* RB = &Rl[b_][0];
        #pragma unroll
        for (int q = 0; q < 6; ++q) {
            int rgn = wid * 6 + q;
            if (rgn < 8) {
                int row = rgn * 8 + lrow;
                gl_lds16(kp + (size_t)(j0n + row) * 64 + scol, KB + rgn * 512);
            } else {
                int row = (rgn - 8) * 8 + lrow;
                int rg = rbase + row;
                rg = rg > 2047 ? 2047 : rg;
                gl_lds16(rp + (size_t)rg * 64 + scol, RB + (rgn - 8) * 512);
            }
        }
        __builtin_amdgcn_sched_barrier(0);
    };

    int buf = 0;
    stage(0, cb_);
    asm volatile("s_waitcnt vmcnt(0)" ::: "memory");
    __builtin_amdgcn_sched_barrier(0);
    __builtin_amdgcn_s_barrier();

    for (int c = cb_; c < ce_; ++c) {
        if (c + 1 < ce_) stage(buf ^ 1, c + 1);   // prefetch next chunk
        int j0 = c * 64;
        int d0 = 1008 + j0 - i0w;
        bool interior = (j0 + 63 <= i0w + M_) && (d0 + 79 <= 2047);
        const ushort* KB = &Kl[buf][0];
        const ushort* RB = &Rl[buf][0];
        f32x4 ac[4];
        #pragma unroll
        for (int su = 0; su < 4; ++su) {
            int row = su * 16 + jl;
            int s0 = (quad ^ jx) * 8;
            bf16x8 k0v = *(const bf16x8*)&KB[row * 64 + s0];
            bf16x8 k1v = *(const bf16x8*)&KB[row * 64 + (s0 ^ 32)];
            f32x4 t = MFMA16(quA[0], k0v, z);
            ac[su] = MFMA16(quA[1], k1v, t);
        }
        int ob = 48 - wid * 16 + jl;
        f32x4 bt[5];
        #pragma unroll
        for (int nt = 0; nt < 5; ++nt) {
            int o = ob + nt * 16;               // 0..127
            int s0 = (quad ^ jx) * 8;
            bf16x8 r0 = *(const bf16x8*)&RB[o * 64 + s0];
            bf16x8 r1 = *(const bf16x8*)&RB[o * 64 + (s0 ^ 32)];
            f32x4 t = MFMA16(qvA[0], r0, z);
            bt[nt] = MFMA16(qvA[1], r1, t);
        }
        float bs[4][5];
        #pragma unroll
        for (int r = 0; r < 4; ++r) {
            int ii = quad * 4 + r;
            int src = (quad << 4) | ((jl + 15 - ii) & 15);
            #pragma unroll
            for (int nt = 0; nt < 5; ++nt) bs[r][nt] = __shfl(bt[nt][r], src);
        }
        if (interior) {
            #pragma unroll
            for (int r = 0; r < 4; ++r) {
                int ii = quad * 4 + r;
                bool hi = (jl > ii);
                u16x4v ps;
                #pragma unroll
                for (int su = 0; su < 4; ++su) {
                    float bd = hi ? bs[r][su + 1] : bs[r][su];
                    float p = EXP2(fminf((ac[su][r] + bd) * SCALE2_, 86.f));
                    lsum[r] += p;
                    ps[su] = f2bf_fast(p);
                }
                *(u16x4v*)(prow0 + (size_t)r * 65536 + j0) = ps;
            }
        } else {
            #pragma unroll
            for (int r = 0; r < 4; ++r) {
                int ii = quad * 4 + r;
                bool hi = (jl > ii);
                u16x4v ps;
                #pragma unroll
                for (int su = 0; su < 4; ++su) {
                    float bd = hi ? bs[r][su + 1] : bs[r][su];
                    float sv = (ac[su][r] + bd) * SCALE2_;
                    int j = j0 + su * 16 + jl;
                    float p = (j <= irow + r + M_) ? EXP2(fminf(sv, 86.f)) : 0.f;
                    lsum[r] += p;
                    ps[su] = f2bf_fast(p);
                }
                *(u16x4v*)(prow0 + (size_t)r * 65536 + j0) = ps;
            }
        }
        asm volatile("s_waitcnt vmcnt(4)" ::: "memory");
        __builtin_amdgcn_sched_barrier(0);
        __builtin_amdgcn_s_barrier();
        buf ^= 1;
    }

    #pragma unroll
    for (int r = 0; r < 4; ++r) {
        #pragma unroll
        for (int off = 1; off < 16; off <<= 1) lsum[r] += __shfl_xor(lsum[r], off);
        if (jl == 0) atomicAdd(&lpart[(size_t)bh * 1024 + irow + r], lsum[r]);
    }
}

// ---------------------------------------------------------------------------
// PV GEMM (round-10 structure + register-prefetch pipeline): 64x64 tiles,
// 512 blocks, K bounded by causal region 64*(17+mt). Next k-slice is loaded
// into registers while the current slice computes; the load's waitcnt lands
// at the next iteration's ds_write -> global latency hidden under MFMA phase.
// P and Vt share the same k-permuted column order -> dot products unchanged.
// ---------------------------------------------------------------------------
__global__ __launch_bounds__(256) void pv_gemm(
    const ushort* __restrict__ P, const ushort* __restrict__ Vt,
    const float* __restrict__ lpart,
    ushort* __restrict__ OvecB, float* __restrict__ linvs)
{
    __shared__ ushort Al[64][40];
    __shared__ ushort Bl[64][40];
    int tid = threadIdx.x;
    int lin  = blockIdx.x;             // 512
    int xcd  = lin & 7;
    int rest = lin >> 3;               // 0..63
    int bh   = (xcd << 2) | (rest & 3);
    int mt   = rest >> 2;              // 0..15
    int M0   = mt * 64;
    int wid = tid >> 6, lane = tid & 63, quad = lane >> 4, jl = lane & 15;
    int m0w = (wid >> 1) * 32, n0w = (wid & 1) * 32;
    int sr = tid >> 2, sc = (tid & 3) * 8;

    const ushort* Bp = Vt + (size_t)bh * 64 * 2048;
    int kend = (17 + mt) * 64;

    const ushort* pA = P + ((size_t)(M0 + sr) * 32 + bh) * 2048 + sc;
    const ushort* pB = Bp + (size_t)sr * 2048 + sc;

    f32x4 acc[2][2];
    #pragma unroll
    for (int i = 0; i < 2; ++i)
        #pragma unroll
        for (int j = 0; j < 2; ++j) acc[i][j] = (f32x4){0.f, 0.f, 0.f, 0.f};

    // prologue: first slice into regs
    u16x8v rA = *(const u16x8v*)(pA);
    u16x8v rB = *(const u16x8v*)(pB);

    for (int k0 = 0; k0 < kend; k0 += 32) {
        __syncthreads();                 // readers of previous slice done
        *(u16x8v*)&Al[sr][sc] = rA;
        *(u16x8v*)&Bl[sr][sc] = rB;
        if (k0 + 32 < kend) {            // issue next loads; wait deferred
            rA = *(const u16x8v*)(pA + k0 + 32);
            rB = *(const u16x8v*)(pB + k0 + 32);
        }
        __syncthreads();                 // slice visible
        bf16x8 a0 = *(const bf16x8*)&Al[m0w + jl][quad * 8];
        bf16x8 a1 = *(const bf16x8*)&Al[m0w + 16 + jl][quad * 8];
        bf16x8 b0 = *(const bf16x8*)&Bl[n0w + jl][quad * 8];
        bf16x8 b1 = *(const bf16x8*)&Bl[n0w + 16 + jl][quad * 8];
        acc[0][0] = MFMA16(a0, b0, acc[0][0]);
        acc[0][1] = MFMA16(a0, b1, acc[0][1]);
        acc[1][0] = MFMA16(a1, b0, acc[1][0]);
        acc[1][1] = MFMA16(a1, b1, acc[1][1]);
    }

    int b = bh >> 4, h = bh & 15;
    #pragma unroll
    for (int ms = 0; ms < 2; ++ms)
        #pragma unroll
        for (int r = 0; r < 4; ++r) {
            int gi = M0 + m0w + 16 * ms + quad * 4 + r;
            float linv = 1.f / lpart[(size_t)bh * 1024 + gi];
            #pragma unroll
            for (int ns = 0; ns < 2; ++ns) {
                int gd = n0w + 16 * ns + jl;
                OvecB[(size_t)(gi * 2 + b) * 1024 + h * 64 + gd] =
                    f2bf(acc[ms][ns][r] * linv);
            }
            if (n0w == 0 && jl == 0)
                linvs[(size_t)gi * 32 + bh] = linv * 0.03125f;
        }
}

// ---------------------------------------------------------------------------
// Fused tail: blocks [0,512) = output projection + residual (64x64 tiles);
// blocks [512,1536) = am_reduce row i = lin-512 (reads k'-permuted planes,
// un-permutes through an 8KB LDS pass before the linear AM write).
// ---------------------------------------------------------------------------
__global__ __launch_bounds__(256) void tail_fused(
    const ushort* __restrict__ A, const ushort* __restrict__ Wt,
    const float* __restrict__ resid, float* __restrict__ outF,
    const ushort* __restrict__ AMw, const float* __restrict__ linvs,
    float* __restrict__ AM)
{
    __shared__ ushort Al[64][40];
    __shared__ ushort Bl[64][40];
    int tid = threadIdx.x;
    int lin = blockIdx.x;
    if (lin >= 512) {
        // ---- am_reduce ----
        __shared__ float lv[32];
        __shared__ float jbuf[2048];
        int i = lin - 512;
        if (tid < 32) lv[tid] = linvs[(size_t)i * 32 + tid];
        __syncthreads();
        int k0 = tid * 8;                  // k' index
        int jmax = i + M_;
        float acc[8];
        #pragma unroll
        for (int e = 0; e < 8; ++e) acc[e] = 0.f;
        if ((k0 & ~63) <= jmax) {          // chunk base <= jmax -> chunk stored
            const ushort* base = AMw + (size_t)i * 65536;
            for (int p = 0; p < 32; ++p) {
                float l = lv[p];
                u16x8v v = *(const u16x8v*)(base + (size_t)p * 2048 + k0);
                #pragma unroll
                for (int e = 0; e < 8; ++e) acc[e] += bf2f(v[e]) * l;
            }
        }
        // un-permute k' -> true j via LDS
        #pragma unroll
        for (int e = 0; e < 8; ++e) {
            int kp = k0 + e;
            int j  = (kp & ~63) | ((kp & 3) << 4) | ((kp >> 2) & 15);
            jbuf[j] = acc[e];
        }
        __syncthreads();
        int j0 = tid * 8;
        float4 o0, o1;
        o0.x = (j0 + 0 <= jmax) ? jbuf[j0 + 0] : 0.f;
        o0.y = (j0 + 1 <= jmax) ? jbuf[j0 + 1] : 0.f;
        o0.z = (j0 + 2 <= jmax) ? jbuf[j0 + 2] : 0.f;
        o0.w = (j0 + 3 <= jmax) ? jbuf[j0 + 3] : 0.f;
        o1.x = (j0 + 4 <= jmax) ? jbuf[j0 + 4] : 0.f;
        o1.y = (j0 + 5 <= jmax) ? jbuf[j0 + 5] : 0.f;
        o1.z = (j0 + 6 <= jmax) ? jbuf[j0 + 6] : 0.f;
        o1.w = (j0 + 7 <= jmax) ? jbuf[j0 + 7] : 0.f;
        *(float4*)(AM + (size_t)i * 2048 + j0) = o0;
        *(float4*)(AM + (size_t)i * 2048 + j0 + 4) = o1;
        return;
    }
    // ---- gemm_o ----
    int M0 = (lin & 31) * 64, N0 = (lin >> 5) * 64;
    int wid = tid >> 6, lane = tid & 63, quad = lane >> 4, jl = lane & 15;
    int m0w = (wid >> 1) * 32, n0w = (wid & 1) * 32;
    int sr = tid >> 2, sc = (tid & 3) * 8;

    f32x4 acc[2][2];
    #pragma unroll
    for (int i = 0; i < 2; ++i)
        #pragma unroll
        for (int j = 0; j < 2; ++j) acc[i][j] = (f32x4){0.f, 0.f, 0.f, 0.f};

    for (int k0 = 0; k0 < 1024; k0 += 32) {
        *(u16x8v*)&Al[sr][sc] = *(const u16x8v*)(A  + (size_t)(M0 + sr) * 1024 + k0 + sc);
        *(u16x8v*)&Bl[sr][sc] = *(const u16x8v*)(Wt + (size_t)(N0 + sr) * 1024 + k0 + sc);
        __syncthreads();
        bf16x8 a0 = *(const bf16x8*)&Al[m0w + jl][quad * 8];
        bf16x8 a1 = *(const bf16x8*)&Al[m0w + 16 + jl][quad * 8];
        bf16x8 b0 = *(const bf16x8*)&Bl[n0w + jl][quad * 8];
        bf16x8 b1 = *(const bf16x8*)&Bl[n0w + 16 + jl][quad * 8];
        acc[0][0] = MFMA16(a0, b0, acc[0][0]);
        acc[0][1] = MFMA16(a0, b1, acc[0][1]);
        acc[1][0] = MFMA16(a1, b0, acc[1][0]);
        acc[1][1] = MFMA16(a1, b1, acc[1][1]);
        __syncthreads();
    }

    #pragma unroll
    for (int ms = 0; ms < 2; ++ms)
        #pragma unroll
        for (int ns = 0; ns < 2; ++ns)
            #pragma unroll
            for (int r = 0; r < 4; ++r) {
                int gm = M0 + m0w + 16 * ms + quad * 4 + r;
                int gn = N0 + n0w + 16 * ns + jl;
                outF[(size_t)gm * 1024 + gn] =
                    acc[ms][ns][r] + resid[(size_t)gm * 1024 + gn];
            }
}

// ---------------------------------------------------------------------------
// LayerNorm over D=1024, one block per row
// ---------------------------------------------------------------------------
__global__ __launch_bounds__(256) void ln_kernel(
    const float* __restrict__ hbuf,
    const float* __restrict__ gamma, const float* __restrict__ beta,
    float* __restrict__ out)
{
    __shared__ float rs[4], rss[4];
    int row = blockIdx.x;
    int tid = threadIdx.x;
    const float* hp = hbuf + (size_t)row * 1024;
    float4 h4 = *(const float4*)(hp + (tid << 2));
    float s = h4.x + h4.y + h4.z + h4.w;
    float ss = h4.x * h4.x + h4.y * h4.y + h4.z * h4.z + h4.w * h4.w;
    #pragma unroll
    for (int o = 32; o > 0; o >>= 1) {
        s  += __shfl_down(s, o);
        ss += __shfl_down(ss, o);
    }
    if ((tid & 63) == 0) { rs[tid >> 6] = s; rss[tid >> 6] = ss; }
    __syncthreads();
    float tot  = rs[0] + rs[1] + rs[2] + rs[3];
    float tots = rss[0] + rss[1] + rss[2] + rss[3];
    float mu = tot * (1.f / 1024.f);
    float var = tots * (1.f / 1024.f) - mu * mu;
    float rstd = rsqrtf(var + 1e-5f);
    float4 g4 = *(const float4*)(gamma + (tid << 2));
    float4 b4 = *(const float4*)(beta + (tid << 2));
    float4 o4;
    o4.x = (h4.x - mu) * rstd * g4.x + b4.x;
    o4.y = (h4.y - mu) * rstd * g4.y + b4.y;
    o4.z = (h4.z - mu) * rstd * g4.z + b4.z;
    o4.w = (h4.w - mu) * rstd * g4.w + b4.w;
    *(float4*)(out + (size_t)row * 1024 + (tid << 2)) = o4;
}

extern "C" void kernel_launch(void* const* d_in, const int* in_sizes, int n_in,
                              void* d_out, int out_size, void* d_ws, size_t ws_size,
                              hipStream_t stream) {
    const float* x       = (const float*)d_in[0];
    const float* pos_emb = (const float*)d_in[1];
    const float* memory  = (const float*)d_in[2];
    const float* bu      = (const float*)d_in[3];
    const float* bv      = (const float*)d_in[4];
    const float* Wq      = (const float*)d_in[6];
    const float* Wkv     = (const float*)d_in[7];
    const float* Wrel    = (const float*)d_in[8];
    const float* Wo      = (const float*)d_in[9];
    const float* gamma   = (const float*)d_in[10];
    const float* beta    = (const float*)d_in[11];

    float* out = (float*)d_out;
    float* AM  = out + (size_t)2097152;       // attn_matrix [L][T]

    ushort* cb    = (ushort*)d_ws;            // [4096][1024]
    ushort* pb    = cb    + 4194304;          // [4096][1024]
    ushort* Wqt   = pb    + 4194304;          // [1024][1024]
    ushort* Wkvt  = Wqt   + 1048576;          // [2048][1024]
    ushort* Wrelt = Wkvt  + 2097152;          // [1024][1024]
    ushort* Wot   = Wrelt + 1048576;          // [1024][1024]
    ushort* quB   = Wot   + 1048576;          // [32][1024][64]
    ushort* qvB   = quB   + 2097152;
    ushort* kbB   = qvB   + 2097152;          // [32][2048][64]
    ushort* VtB   = kbB   + 4194304;          // [32][64][2048] (k-permuted cols)
    ushort* rbB   = VtB   + 4194304;          // [32][2048][64]
    ushort* OvecB = rbB   + 4194304;          // [2048][1024]
    float*  hbuf  = (float*)(OvecB + 2097152);// [2048][1024] fp32
    float*  lpart = hbuf  + 2097152;          // [32][1024] fp32
    float*  linvs = lpart + 32768;            // [1024][32] fp32
    ushort* AMw   = (ushort*)(linvs + 32768); // [1024][32][2048] bf16 k-permuted

    dim3 blk(256);
    // fused converts + weight transposes + lpart clear
    prep<<<9248, blk, 0, stream>>>(memory, x, pos_emb, Wq, Wkv, Wrel, Wo,
                                   cb, pb, Wqt, Wkvt, Wrelt, Wot, lpart);
    // all projections: 256^2 tiles, 8 waves, vectorized VtB epilogue
    proj_all<<<224, dim3(512), 0, stream>>>(cb, pb, Wqt, Wkvt, Wrelt, bu, bv,
                                            quB, qvB, kbB, VtB, rbB);
    // scores -> planes (block-coop LDS staging, counted vmcnt, raw barriers)
    attn_score<<<dim3(2720), blk, 0, stream>>>(quB, qvB, kbB, rbB, lpart, AMw);
    // PV as causal-K GEMM with register-prefetch pipeline; folds o_combine
    pv_gemm<<<dim3(512), blk, 0, stream>>>(AMw, VtB, lpart, OvecB, linvs);
    // fused output projection + attn_matrix reduction
    tail_fused<<<dim3(1536), blk, 0, stream>>>(OvecB, Wot, x, hbuf,
                                               AMw, linvs, AM);
    // layernorm
    ln_kernel<<<2048, blk, 0, stream>>>(hbuf, gamma, beta, out);
}

// Round 13
// 268.372 us; speedup vs baseline: 1.0845x; 1.0196x over previous
//
#include <hip/hip_runtime.h>
#include <math.h>
#include <stdint.h>

#define L_  1024
#define B_  2
#define D_  1024
#define H_  16
#define DH_ 64
#define M_  1024
#define T_  2048
#define SCALE_ 0.125f
#define SCALE2_ 0.18033688f   // 0.125 * log2(e)

typedef unsigned short ushort;
typedef short bf16x8 __attribute__((ext_vector_type(8)));
typedef float f32x4 __attribute__((ext_vector_type(4)));
typedef unsigned short u16x4v __attribute__((ext_vector_type(4)));
typedef unsigned short u16x8v __attribute__((ext_vector_type(8)));

#define MFMA16(a,b,c) __builtin_amdgcn_mfma_f32_16x16x32_bf16(a,b,c,0,0,0)

#if __has_builtin(__builtin_amdgcn_exp2f)
#define EXP2(x) __builtin_amdgcn_exp2f(x)
#else
#define EXP2(x) exp2f(x)
#endif

static __device__ __forceinline__ ushort f2bf(float x) {
    uint32_t u = __float_as_uint(x);
    uint32_t r = (u + 0x7FFFu + ((u >> 16) & 1u)) >> 16;
    return (ushort)r;
}
// fast round-half-up (hot path only; <=0.5 ULP bias, fine vs 0.0988 threshold)
static __device__ __forceinline__ ushort f2bf_fast(float x) {
    return (ushort)((__float_as_uint(x) + 0x8000u) >> 16);
}
static __device__ __forceinline__ float bf2f(ushort h) {
    return __uint_as_float(((uint32_t)h) << 16);
}
// async global->LDS, 16B per lane; LDS dest = wave-uniform base + lane*16
static __device__ __forceinline__ void gl_lds16(const ushort* g, ushort* l) {
    __builtin_amdgcn_global_load_lds(
        (const __attribute__((address_space(1))) void*)g,
        (__attribute__((address_space(3))) void*)l, 16, 0, 0);
}

// slice tables: grp g has nc=17+g chunks split into ns=ceil(nc/5) slices.
// 85 slices per bh plane -> grid 32*85 = 2720, every slice <=5 chunks.
static __device__ const unsigned char GRP_OF[85] = {
 0,0,0,0, 1,1,1,1, 2,2,2,2, 3,3,3,3,
 4,4,4,4,4, 5,5,5,5,5, 6,6,6,6,6, 7,7,7,7,7, 8,8,8,8,8,
 9,9,9,9,9,9, 10,10,10,10,10,10, 11,11,11,11,11,11,
 12,12,12,12,12,12, 13,13,13,13,13,13,
 14,14,14,14,14,14,14, 15,15,15,15,15,15,15};
static __device__ const unsigned char SLC_OF[85] = {
 0,1,2,3, 0,1,2,3, 0,1,2,3, 0,1,2,3,
 0,1,2,3,4, 0,1,2,3,4, 0,1,2,3,4, 0,1,2,3,4, 0,1,2,3,4,
 0,1,2,3,4,5, 0,1,2,3,4,5, 0,1,2,3,4,5,
 0,1,2,3,4,5, 0,1,2,3,4,5,
 0,1,2,3,4,5,6, 0,1,2,3,4,5,6};
static __device__ const unsigned char NS_OF[16] = {4,4,4,4,5,5,5,5,5,6,6,6,6,6,7,7};

// ---------------------------------------------------------------------------
// Fused prep: fp32->bf16 converts (blocks 0..4095), weight transposes
// (4096..9215), lpart zero-fill (9216..9247).
// ---------------------------------------------------------------------------
__global__ __launch_bounds__(256) void prep(
    const float* __restrict__ memory, const float* __restrict__ x,
    const float* __restrict__ pos_emb,
    const float* __restrict__ Wq, const float* __restrict__ Wkv,
    const float* __restrict__ Wrel, const float* __restrict__ Wo,
    ushort* __restrict__ cb, ushort* __restrict__ pb,
    ushort* __restrict__ Wqt, ushort* __restrict__ Wkvt,
    ushort* __restrict__ Wrelt, ushort* __restrict__ Wot,
    float* __restrict__ lpart)
{
    __shared__ float t[32][33];
    int tid = threadIdx.x;
    if (blockIdx.x >= 9216) {
        int i = ((blockIdx.x - 9216) * 256 + tid) * 4;
        *(float4*)(lpart + i) = (float4){0.f, 0.f, 0.f, 0.f};
        return;
    }
    if (blockIdx.x < 4096) {
        int idx = (blockIdx.x * 256 + tid) * 8;
        const float* s;
        ushort* d;
        if (idx < 2097152)      { s = memory + idx;              d = cb + idx; }
        else if (idx < 4194304) { s = x + (idx - 2097152);       d = cb + idx; }
        else                    { s = pos_emb + (idx - 4194304); d = pb + (idx - 4194304); }
        float4 a = *(const float4*)(s);
        float4 b = *(const float4*)(s + 4);
        u16x8v o;
        o[0] = f2bf(a.x); o[1] = f2bf(a.y); o[2] = f2bf(a.z); o[3] = f2bf(a.w);
        o[4] = f2bf(b.x); o[5] = f2bf(b.y); o[6] = f2bf(b.z); o[7] = f2bf(b.w);
        *(u16x8v*)d = o;
        return;
    }
    int tb = blockIdx.x - 4096;
    const float* src; ushort* dst; int N;
    if (tb < 1024)      { src = Wq;   dst = Wqt;   N = 1024; }
    else if (tb < 3072) { src = Wkv;  dst = Wkvt;  N = 2048; tb -= 1024; }
    else if (tb < 4096) { src = Wrel; dst = Wrelt; N = 1024; tb -= 3072; }
    else                { src = Wo;   dst = Wot;   N = 1024; tb -= 4096; }
    int k0 = (tb & 31) * 32, n0 = (tb >> 5) * 32;
    int r = tid >> 3, c4 = (tid & 7) * 4;
    float4 v = *(const float4*)(src + (size_t)(k0 + r) * N + n0 + c4);
    t[r][c4 + 0] = v.x; t[r][c4 + 1] = v.y; t[r][c4 + 2] = v.z; t[r][c4 + 3] = v.w;
    __syncthreads();
    u16x4v o;
    o[0] = f2bf(t[c4 + 0][r]); o[1] = f2bf(t[c4 + 1][r]);
    o[2] = f2bf(t[c4 + 2][r]); o[3] = f2bf(t[c4 + 3][r]);
    *(u16x4v*)(dst + (size_t)(n0 + r) * 1024 + k0 + c4) = o;
}

// ---------------------------------------------------------------------------
// Single-launch projections, 256x256 tiles, 512 threads (8 waves, 2x4 grid,
// 128x64 output per wave). Triple-buffered BK=32 staging, 2-deep prefetch,
// counted vmcnt(4), literal buffer indices. Vectorized VtB epilogue (16B
// u16x8v stores along t'). Grid 224 blocks.
// ---------------------------------------------------------------------------
__global__ __launch_bounds__(512) void proj_all(
    const ushort* __restrict__ cb, const ushort* __restrict__ pb,
    const ushort* __restrict__ Wqt, const ushort* __restrict__ Wkvt,
    const ushort* __restrict__ Wrelt,
    const float* __restrict__ bu, const float* __restrict__ bv,
    ushort* __restrict__ quB, ushort* __restrict__ qvB,
    ushort* __restrict__ kbB, ushort* __restrict__ VtB,
    ushort* __restrict__ rbB)
{
    __shared__ ushort Al[3][256 * 32];    // 3 x 16 KB
    __shared__ ushort Bl[3][256 * 32];    // 3 x 16 KB  (total 96 KB)
    int lin = blockIdx.x;
    int omode, M0, N0;
    const ushort *A, *Wt;
    if (lin < 32) {
        omode = 0; A = cb + 2097152; Wt = Wqt;
        M0 = (lin & 7) * 256; N0 = (lin >> 3) * 256;
    } else if (lin < 160) {
        omode = 1; A = cb; Wt = Wkvt;
        int l2 = lin - 32;
        M0 = (l2 & 15) * 256; N0 = (l2 >> 4) * 256;
    } else {
        omode = 2; A = pb; Wt = Wrelt;
        int l2 = lin - 160;
        M0 = (l2 & 15) * 256; N0 = (l2 >> 4) * 256;
    }
    int tid = threadIdx.x;
    int wid = tid >> 6, lane = tid & 63, quad = lane >> 4, jl = lane & 15;
    int wr = wid >> 2, wc = wid & 3;      // 2 x 4 wave grid
    int srow = lane >> 2;                 // row within 16-row chunk

    f32x4 acc[8][4];
    #pragma unroll
    for (int i = 0; i < 8; ++i)
        #pragma unroll
        for (int j = 0; j < 4; ++j) acc[i][j] = (f32x4){0.f, 0.f, 0.f, 0.f};

    auto stage = [&](int b_, int k0) {
        #pragma unroll
        for (int c = 0; c < 2; ++c) {
            int chunk = wid * 2 + c;                    // 0..15
            int r  = chunk * 16 + srow;                 // tile row 0..255
            int su = ((lane & 3) - (r >> 1)) & 3;       // source 16B unit
            gl_lds16(A  + (size_t)(M0 + r) * 1024 + k0 + su * 8,
                     &Al[b_][chunk * 512]);
            gl_lds16(Wt + (size_t)(N0 + r) * 1024 + k0 + su * 8,
                     &Bl[b_][chunk * 512]);
        }
        __builtin_amdgcn_sched_barrier(0);
    };

#define PROJ_STEP(IDX, BUF, SBUF, WAITN)                                    \
    {                                                                       \
        asm volatile("s_waitcnt vmcnt(" #WAITN ")" ::: "memory");           \
        __builtin_amdgcn_sched_barrier(0);                                  \
        __builtin_amdgcn_s_barrier();                                       \
        if ((IDX) + 2 < 32) stage((SBUF), ((IDX) + 2) * 32);                \
        bf16x8 af[8], bfr[4];                                               \
        _Pragma("unroll")                                                   \
        for (int mt = 0; mt < 8; ++mt) {                                    \
            int ra = wr * 128 + mt * 16 + jl;                               \
            int u  = (quad + (ra >> 1)) & 3;                                \
            af[mt] = *(const bf16x8*)&Al[(BUF)][ra * 32 + u * 8];           \
        }                                                                   \
        _Pragma("unroll")                                                   \
        for (int nt = 0; nt < 4; ++nt) {                                    \
            int rb_ = wc * 64 + nt * 16 + jl;                               \
            int u   = (quad + (rb_ >> 1)) & 3;                              \
            bfr[nt] = *(const bf16x8*)&Bl[(BUF)][rb_ * 32 + u * 8];         \
        }                                                                   \
        _Pragma("unroll")                                                   \
        for (int mt = 0; mt < 8; ++mt)                                      \
            _Pragma("unroll")                                               \
            for (int nt = 0; nt < 4; ++nt)                                  \
                acc[mt][nt] = MFMA16(af[mt], bfr[nt], acc[mt][nt]);         \
    }

    stage(0, 0);
    stage(1, 32);

    #pragma unroll 1
    for (int i3 = 0; i3 < 30; i3 += 3) {
        PROJ_STEP(i3 + 0, 0, 2, 4);
        PROJ_STEP(i3 + 1, 1, 0, 4);
        PROJ_STEP(i3 + 2, 2, 1, 4);
    }
    PROJ_STEP(30, 0, 2, 4);   // i+2=32: no stage issued
    PROJ_STEP(31, 1, 0, 0);   // final drain
#undef PROJ_STEP

    if (omode == 0) {
        #pragma unroll
        for (int mt = 0; mt < 8; ++mt)
            #pragma unroll
            for (int nt = 0; nt < 4; ++nt)
                #pragma unroll
                for (int r = 0; r < 4; ++r) {
                    int gm = M0 + wr * 128 + mt * 16 + quad * 4 + r;
                    int gn = N0 + wc * 64 + nt * 16 + jl;
                    float v = acc[mt][nt][r];
                    int l = gm >> 1, b = gm & 1;
                    int h = gn >> 6, d = gn & 63;
                    size_t o = ((size_t)((b << 4) | h) * 1024 + l) * 64 + d;
                    quB[o] = f2bf(v + bu[gn]);
                    qvB[o] = f2bf(v + bv[gn]);
                }
    } else if (omode == 2) {
        #pragma unroll
        for (int mt = 0; mt < 8; ++mt)
            #pragma unroll
            for (int nt = 0; nt < 4; ++nt)
                #pragma unroll
                for (int r = 0; r < 4; ++r) {
                    int gm = M0 + wr * 128 + mt * 16 + quad * 4 + r;
                    int gn = N0 + wc * 64 + nt * 16 + jl;
                    int t2 = gm >> 1, b = gm & 1;
                    int h = gn >> 6, d = gn & 63;
                    rbB[((size_t)((b << 4) | h) * 2048 + t2) * 64 + d] =
                        f2bf(acc[mt][nt][r]);
                }
    } else if (N0 < 1024) {
        #pragma unroll
        for (int mt = 0; mt < 8; ++mt)
            #pragma unroll
            for (int nt = 0; nt < 4; ++nt)
                #pragma unroll
                for (int r = 0; r < 4; ++r) {
                    int gm = M0 + wr * 128 + mt * 16 + quad * 4 + r;
                    int gn = N0 + wc * 64 + nt * 16 + jl;
                    int t2 = gm >> 1, b = gm & 1;
                    int h = gn >> 6, d = gn & 63;
                    kbB[((size_t)((b << 4) | h) * 2048 + t2) * 64 + d] =
                        f2bf(acc[mt][nt][r]);
                }
    } else {
        // VtB half, vectorized along t' (verified index-by-index)
        #pragma unroll
        for (int nt = 0; nt < 4; ++nt) {
            int nn = (N0 + wc * 64 + nt * 16 + jl) & 1023;
            int h = nn >> 6, d = nn & 63;
            #pragma unroll
            for (int g = 0; g < 2; ++g)
                #pragma unroll
                for (int b = 0; b < 2; ++b) {
                    u16x8v pk;
                    #pragma unroll
                    for (int e = 0; e < 8; ++e)
                        pk[e] = f2bf(acc[2 * (e & 3) + g][nt][b + 2 * (e >> 2)]);
                    size_t tp = (size_t)(M0 >> 1) + wr * 64 + g * 32 + quad * 8;
                    *(u16x8v*)(VtB + ((size_t)((b << 4) | h) * 64 + d) * 2048 + tp) = pk;
                }
        }
    }
}

// ---------------------------------------------------------------------------
// Score kernel: block-cooperative double-buffered LDS staging of K and R via
// global_load_lds; XOR source-swizzle; counted vmcnt(4) + raw s_barrier.
// Output: direct k'-permuted 8B/lane stores.
// ---------------------------------------------------------------------------
__global__ __launch_bounds__(256) void attn_score(
    const ushort* __restrict__ qu, const ushort* __restrict__ qv,
    const ushort* __restrict__ kb, const ushort* __restrict__ rb,
    float* __restrict__ lpart, ushort* __restrict__ AMw)
{
    __shared__ ushort Kl[2][64 * 64];     // 16 KB
    __shared__ ushort Rl[2][128 * 64];    // 32 KB

    int tid = threadIdx.x, wid = tid >> 6, lane = tid & 63;
    int quad = lane >> 4, jl = lane & 15, jx = jl & 7;

    int lin  = blockIdx.x;             // 2720
    int xcd  = lin & 7;
    int rest = lin >> 3;               // 0..339
    int bh   = (xcd << 2) | (rest & 3);
    int sidx = rest >> 2;              // 0..84
    int grp  = GRP_OF[sidx];
    int slc  = SLC_OF[sidx];
    int nc   = 17 + grp;
    int ns   = NS_OF[grp];
    int cb_  = slc * nc / ns;
    int ce_  = (slc + 1) * nc / ns;
    int it   = grp * 4 + wid;
    int i0w  = it * 16;
    int irow = i0w + quad * 4;

    const ushort* kp  = kb + (size_t)bh * 2048 * 64;
    const ushort* rp  = rb + (size_t)bh * 2048 * 64;
    const ushort* qup = qu + (size_t)bh * 1024 * 64;
    const ushort* qvp = qv + (size_t)bh * 1024 * 64;

    bf16x8 quA[2], qvA[2];
    quA[0] = *(const bf16x8*)(qup + (size_t)(i0w + jl) * 64 + quad * 8);
    quA[1] = *(const bf16x8*)(qup + (size_t)(i0w + jl) * 64 + 32 + quad * 8);
    qvA[0] = *(const bf16x8*)(qvp + (size_t)(i0w + jl) * 64 + quad * 8);
    qvA[1] = *(const bf16x8*)(qvp + (size_t)(i0w + jl) * 64 + 32 + quad * 8);

    ushort* prow0 = AMw + ((size_t)irow * 32 + bh) * 2048 + jl * 4;

    int lrow = lane >> 3;                    // 0..7 = row within region
    int scol = ((lane & 7) ^ lrow) * 8;      // source col (elements)

    f32x4 z = (f32x4){0.f, 0.f, 0.f, 0.f};
    float lsum[4] = {0.f, 0.f, 0.f, 0.f};

    auto stage = [&](int b_, int c) {
        int j0n = c * 64;
        int rbase = 960 + j0n - grp * 64;    // always >= 0
        ushort* KB = &Kl[b_][0];
        ushort* RB = &Rl[b_][0];
        #pragma unroll
        for (int q = 0; q < 6; ++q) {
            int rgn = wid * 6 + q;
            if (rgn < 8) {
                int row = rgn * 8 + lrow;
                gl_lds16(kp + (size_t)(j0n + row) * 64 + scol, KB + rgn * 512);
            } else {
                int row = (rgn - 8) * 8 + lrow;
                int rg = rbase + row;
                rg = rg > 2047 ? 2047 : rg;
                gl_lds16(rp + (size_t)rg * 64 + scol, RB + (rgn - 8) * 512);
            }
        }
        __builtin_amdgcn_sched_barrier(0);
    };

    int buf = 0;
    stage(0, cb_);
    asm volatile("s_waitcnt vmcnt(0)" ::: "memory");
    __builtin_amdgcn_sched_barrier(0);
    __builtin_amdgcn_s_barrier();

    for (int c = cb_; c < ce_; ++c) {
        if (c + 1 < ce_) stage(buf ^ 1, c + 1);   // prefetch next chunk
        int j0 = c * 64;
        int d0 = 1008 + j0 - i0w;
        bool interior = (j0 + 63 <= i0w + M_) && (d0 + 79 <= 2047);
        const ushort* KB = &Kl[buf][0];
        const ushort* RB = &Rl[buf][0];
        f32x4 ac[4];
        #pragma unroll
        for (int su = 0; su < 4; ++su) {
            int row = su * 16 + jl;
            int s0 = (quad ^ jx) * 8;
            bf16x8 k0v = *(const bf16x8*)&KB[row * 64 + s0];
            bf16x8 k1v = *(const bf16x8*)&KB[row * 64 + (s0 ^ 32)];
            f32x4 t = MFMA16(quA[0], k0v, z);
            ac[su] = MFMA16(quA[1], k1v, t);
        }
        int ob = 48 - wid * 16 + jl;
        f32x4 bt[5];
        #pragma unroll
        for (int nt = 0; nt < 5; ++nt) {
            int o = ob + nt * 16;               // 0..127
            int s0 = (quad ^ jx) * 8;
            bf16x8 r0 = *(const bf16x8*)&RB[o * 64 + s0];
            bf16x8 r1 = *(const bf16x8*)&RB[o * 64 + (s0 ^ 32)];
            f32x4 t = MFMA16(qvA[0], r0, z);
            bt[nt] = MFMA16(qvA[1], r1, t);
        }
        float bs[4][5];
        #pragma unroll
        for (int r = 0; r < 4; ++r) {
            int ii = quad * 4 + r;
            int src = (quad << 4) | ((jl + 15 - ii) & 15);
            #pragma unroll
            for (int nt = 0; nt < 5; ++nt) bs[r][nt] = __shfl(bt[nt][r], src);
        }
        if (interior) {
            #pragma unroll
            for (int r = 0; r < 4; ++r) {
                int ii = quad * 4 + r;
                bool hi = (jl > ii);
                u16x4v ps;
                #pragma unroll
                for (int su = 0; su < 4; ++su) {
                    float bd = hi ? bs[r][su + 1] : bs[r][su];
                    float p = EXP2(fminf((ac[su][r] + bd) * SCALE2_, 86.f));
                    lsum[r] += p;
                    ps[su] = f2bf_fast(p);
                }
                *(u16x4v*)(prow0 + (size_t)r * 65536 + j0) = ps;
            }
        } else {
            #pragma unroll
            for (int r = 0; r < 4; ++r) {
                int ii = quad * 4 + r;
                bool hi = (jl > ii);
                u16x4v ps;
                #pragma unroll
                for (int su = 0; su < 4; ++su) {
                    float bd = hi ? bs[r][su + 1] : bs[r][su];
                    float sv = (ac[su][r] + bd) * SCALE2_;
                    int j = j0 + su * 16 + jl;
                    float p = (j <= irow + r + M_) ? EXP2(fminf(sv, 86.f)) : 0.f;
                    lsum[r] += p;
                    ps[su] = f2bf_fast(p);
                }
                *(u16x4v*)(prow0 + (size_t)r * 65536 + j0) = ps;
            }
        }
        asm volatile("s_waitcnt vmcnt(4)" ::: "memory");
        __builtin_amdgcn_sched_barrier(0);
        __builtin_amdgcn_s_barrier();
        buf ^= 1;
    }

    #pragma unroll
    for (int r = 0; r < 4; ++r) {
        #pragma unroll
        for (int off = 1; off < 16; off <<= 1) lsum[r] += __shfl_xor(lsum[r], off);
        if (jl == 0) atomicAdd(&lpart[(size_t)bh * 1024 + irow + r], lsum[r]);
    }
}

// ---------------------------------------------------------------------------
// PV GEMM (round-12: register-prefetch pipeline): 64x64 tiles, 512 blocks,
// K bounded by causal region 64*(17+mt). Folds o_combine.
// ---------------------------------------------------------------------------
__global__ __launch_bounds__(256) void pv_gemm(
    const ushort* __restrict__ P, const ushort* __restrict__ Vt,
    const float* __restrict__ lpart,
    ushort* __restrict__ OvecB, float* __restrict__ linvs)
{
    __shared__ ushort Al[64][40];
    __shared__ ushort Bl[64][40];
    int tid = threadIdx.x;
    int lin  = blockIdx.x;             // 512
    int xcd  = lin & 7;
    int rest = lin >> 3;               // 0..63
    int bh   = (xcd << 2) | (rest & 3);
    int mt   = rest >> 2;              // 0..15
    int M0   = mt * 64;
    int wid = tid >> 6, lane = tid & 63, quad = lane >> 4, jl = lane & 15;
    int m0w = (wid >> 1) * 32, n0w = (wid & 1) * 32;
    int sr = tid >> 2, sc = (tid & 3) * 8;

    const ushort* Bp = Vt + (size_t)bh * 64 * 2048;
    int kend = (17 + mt) * 64;

    const ushort* pA = P + ((size_t)(M0 + sr) * 32 + bh) * 2048 + sc;
    const ushort* pB = Bp + (size_t)sr * 2048 + sc;

    f32x4 acc[2][2];
    #pragma unroll
    for (int i = 0; i < 2; ++i)
        #pragma unroll
        for (int j = 0; j < 2; ++j) acc[i][j] = (f32x4){0.f, 0.f, 0.f, 0.f};

    // prologue: first slice into regs
    u16x8v rA = *(const u16x8v*)(pA);
    u16x8v rB = *(const u16x8v*)(pB);

    for (int k0 = 0; k0 < kend; k0 += 32) {
        __syncthreads();                 // readers of previous slice done
        *(u16x8v*)&Al[sr][sc] = rA;
        *(u16x8v*)&Bl[sr][sc] = rB;
        if (k0 + 32 < kend) {            // issue next loads; wait deferred
            rA = *(const u16x8v*)(pA + k0 + 32);
            rB = *(const u16x8v*)(pB + k0 + 32);
        }
        __syncthreads();                 // slice visible
        bf16x8 a0 = *(const bf16x8*)&Al[m0w + jl][quad * 8];
        bf16x8 a1 = *(const bf16x8*)&Al[m0w + 16 + jl][quad * 8];
        bf16x8 b0 = *(const bf16x8*)&Bl[n0w + jl][quad * 8];
        bf16x8 b1 = *(const bf16x8*)&Bl[n0w + 16 + jl][quad * 8];
        acc[0][0] = MFMA16(a0, b0, acc[0][0]);
        acc[0][1] = MFMA16(a0, b1, acc[0][1]);
        acc[1][0] = MFMA16(a1, b0, acc[1][0]);
        acc[1][1] = MFMA16(a1, b1, acc[1][1]);
    }

    int b = bh >> 4, h = bh & 15;
    #pragma unroll
    for (int ms = 0; ms < 2; ++ms)
        #pragma unroll
        for (int r = 0; r < 4; ++r) {
            int gi = M0 + m0w + 16 * ms + quad * 4 + r;
            float linv = 1.f / lpart[(size_t)bh * 1024 + gi];
            #pragma unroll
            for (int ns = 0; ns < 2; ++ns) {
                int gd = n0w + 16 * ns + jl;
                OvecB[(size_t)(gi * 2 + b) * 1024 + h * 64 + gd] =
                    f2bf(acc[ms][ns][r] * linv);
            }
            if (n0w == 0 && jl == 0)
                linvs[(size_t)gi * 32 + bh] = linv * 0.03125f;
        }
}

// ---------------------------------------------------------------------------
// Fused tail: blocks [0,512) = output projection + residual (64x64 tiles,
// round-13: register-prefetch pipeline identical to pv_gemm's);
// blocks [512,1536) = am_reduce row i = lin-512 (reads k'-permuted planes,
// un-permutes through an 8KB LDS pass before the linear AM write).
// ---------------------------------------------------------------------------
__global__ __launch_bounds__(256) void tail_fused(
    const ushort* __restrict__ A, const ushort* __restrict__ Wt,
    const float* __restrict__ resid, float* __restrict__ outF,
    const ushort* __restrict__ AMw, const float* __restrict__ linvs,
    float* __restrict__ AM)
{
    __shared__ ushort Al[64][40];
    __shared__ ushort Bl[64][40];
    int tid = threadIdx.x;
    int lin = blockIdx.x;
    if (lin >= 512) {
        // ---- am_reduce ----
        __shared__ float lv[32];
        __shared__ float jbuf[2048];
        int i = lin - 512;
        if (tid < 32) lv[tid] = linvs[(size_t)i * 32 + tid];
        __syncthreads();
        int k0 = tid * 8;                  // k' index
        int jmax = i + M_;
        float acc[8];
        #pragma unroll
        for (int e = 0; e < 8; ++e) acc[e] = 0.f;
        if ((k0 & ~63) <= jmax) {          // chunk base <= jmax -> chunk stored
            const ushort* base = AMw + (size_t)i * 65536;
            for (int p = 0; p < 32; ++p) {
                float l = lv[p];
                u16x8v v = *(const u16x8v*)(base + (size_t)p * 2048 + k0);
                #pragma unroll
                for (int e = 0; e < 8; ++e) acc[e] += bf2f(v[e]) * l;
            }
        }
        // un-permute k' -> true j via LDS
        #pragma unroll
        for (int e = 0; e < 8; ++e) {
            int kp = k0 + e;
            int j  = (kp & ~63) | ((kp & 3) << 4) | ((kp >> 2) & 15);
            jbuf[j] = acc[e];
        }
        __syncthreads();
        int j0 = tid * 8;
        float4 o0, o1;
        o0.x = (j0 + 0 <= jmax) ? jbuf[j0 + 0] : 0.f;
        o0.y = (j0 + 1 <= jmax) ? jbuf[j0 + 1] : 0.f;
        o0.z = (j0 + 2 <= jmax) ? jbuf[j0 + 2] : 0.f;
        o0.w = (j0 + 3 <= jmax) ? jbuf[j0 + 3] : 0.f;
        o1.x = (j0 + 4 <= jmax) ? jbuf[j0 + 4] : 0.f;
        o1.y = (j0 + 5 <= jmax) ? jbuf[j0 + 5] : 0.f;
        o1.z = (j0 + 6 <= jmax) ? jbuf[j0 + 6] : 0.f;
        o1.w = (j0 + 7 <= jmax) ? jbuf[j0 + 7] : 0.f;
        *(float4*)(AM + (size_t)i * 2048 + j0) = o0;
        *(float4*)(AM + (size_t)i * 2048 + j0 + 4) = o1;
        return;
    }
    // ---- gemm_o (register-prefetch pipeline) ----
    int M0 = (lin & 31) * 64, N0 = (lin >> 5) * 64;
    int wid = tid >> 6, lane = tid & 63, quad = lane >> 4, jl = lane & 15;
    int m0w = (wid >> 1) * 32, n0w = (wid & 1) * 32;
    int sr = tid >> 2, sc = (tid & 3) * 8;

    const ushort* pA = A  + (size_t)(M0 + sr) * 1024 + sc;
    const ushort* pB = Wt + (size_t)(N0 + sr) * 1024 + sc;

    f32x4 acc[2][2];
    #pragma unroll
    for (int i = 0; i < 2; ++i)
        #pragma unroll
        for (int j = 0; j < 2; ++j) acc[i][j] = (f32x4){0.f, 0.f, 0.f, 0.f};

    // prologue: first slice into regs
    u16x8v rA = *(const u16x8v*)(pA);
    u16x8v rB = *(const u16x8v*)(pB);

    for (int k0 = 0; k0 < 1024; k0 += 32) {
        __syncthreads();                 // readers of previous slice done
        *(u16x8v*)&Al[sr][sc] = rA;
        *(u16x8v*)&Bl[sr][sc] = rB;
        if (k0 + 32 < 1024) {            // issue next loads; wait deferred
            rA = *(const u16x8v*)(pA + k0 + 32);
            rB = *(const u16x8v*)(pB + k0 + 32);
        }
        __syncthreads();                 // slice visible
        bf16x8 a0 = *(const bf16x8*)&Al[m0w + jl][quad * 8];
        bf16x8 a1 = *(const bf16x8*)&Al[m0w + 16 + jl][quad * 8];
        bf16x8 b0 = *(const bf16x8*)&Bl[n0w + jl][quad * 8];
        bf16x8 b1 = *(const bf16x8*)&Bl[n0w + 16 + jl][quad * 8];
        acc[0][0] = MFMA16(a0, b0, acc[0][0]);
        acc[0][1] = MFMA16(a0, b1, acc[0][1]);
        acc[1][0] = MFMA16(a1, b0, acc[1][0]);
        acc[1][1] = MFMA16(a1, b1, acc[1][1]);
    }

    #pragma unroll
    for (int ms = 0; ms < 2; ++ms)
        #pragma unroll
        for (int ns = 0; ns < 2; ++ns)
            #pragma unroll
            for (int r = 0; r < 4; ++r) {
                int gm = M0 + m0w + 16 * ms + quad * 4 + r;
                int gn = N0 + n0w + 16 * ns + jl;
                outF[(size_t)gm * 1024 + gn] =
                    acc[ms][ns][r] + resid[(size_t)gm * 1024 + gn];
            }
}

// ---------------------------------------------------------------------------
// LayerNorm over D=1024, one block per row
// ---------------------------------------------------------------------------
__global__ __launch_bounds__(256) void ln_kernel(
    const float* __restrict__ hbuf,
    const float* __restrict__ gamma, const float* __restrict__ beta,
    float* __restrict__ out)
{
    __shared__ float rs[4], rss[4];
    int row = blockIdx.x;
    int tid = threadIdx.x;
    const float* hp = hbuf + (size_t)row * 1024;
    float4 h4 = *(const float4*)(hp + (tid << 2));
    float s = h4.x + h4.y + h4.z + h4.w;
    float ss = h4.x * h4.x + h4.y * h4.y + h4.z * h4.z + h4.w * h4.w;
    #pragma unroll
    for (int o = 32; o > 0; o >>= 1) {
        s  += __shfl_down(s, o);
        ss += __shfl_down(ss, o);
    }
    if ((tid & 63) == 0) { rs[tid >> 6] = s; rss[tid >> 6] = ss; }
    __syncthreads();
    float tot  = rs[0] + rs[1] + rs[2] + rs[3];
    float tots = rss[0] + rss[1] + rss[2] + rss[3];
    float mu = tot * (1.f / 1024.f);
    float var = tots * (1.f / 1024.f) - mu * mu;
    float rstd = rsqrtf(var + 1e-5f);
    float4 g4 = *(const float4*)(gamma + (tid << 2));
    float4 b4 = *(const float4*)(beta + (tid << 2));
    float4 o4;
    o4.x = (h4.x - mu) * rstd * g4.x + b4.x;
    o4.y = (h4.y - mu) * rstd * g4.y + b4.y;
    o4.z = (h4.z - mu) * rstd * g4.z + b4.z;
    o4.w = (h4.w - mu) * rstd * g4.w + b4.w;
    *(float4*)(out + (size_t)row * 1024 + (tid << 2)) = o4;
}

extern "C" void kernel_launch(void* const* d_in, const int* in_sizes, int n_in,
                              void* d_out, int out_size, void* d_ws, size_t ws_size,
                              hipStream_t stream) {
    const float* x       = (const float*)d_in[0];
    const float* pos_emb = (const float*)d_in[1];
    const float* memory  = (const float*)d_in[2];
    const float* bu      = (const float*)d_in[3];
    const float* bv      = (const float*)d_in[4];
    const float* Wq      = (const float*)d_in[6];
    const float* Wkv     = (const float*)d_in[7];
    const float* Wrel    = (const float*)d_in[8];
    const float* Wo      = (const float*)d_in[9];
    const float* gamma   = (const float*)d_in[10];
    const float* beta    = (const float*)d_in[11];

    float* out = (float*)d_out;
    float* AM  = out + (size_t)2097152;       // attn_matrix [L][T]

    ushort* cb    = (ushort*)d_ws;            // [4096][1024]
    ushort* pb    = cb    + 4194304;          // [4096][1024]
    ushort* Wqt   = pb    + 4194304;          // [1024][1024]
    ushort* Wkvt  = Wqt   + 1048576;          // [2048][1024]
    ushort* Wrelt = Wkvt  + 2097152;          // [1024][1024]
    ushort* Wot   = Wrelt + 1048576;          // [1024][1024]
    ushort* quB   = Wot   + 1048576;          // [32][1024][64]
    ushort* qvB   = quB   + 2097152;
    ushort* kbB   = qvB   + 2097152;          // [32][2048][64]
    ushort* VtB   = kbB   + 4194304;          // [32][64][2048] (k-permuted cols)
    ushort* rbB   = VtB   + 4194304;          // [32][2048][64]
    ushort* OvecB = rbB   + 4194304;          // [2048][1024]
    float*  hbuf  = (float*)(OvecB + 2097152);// [2048][1024] fp32
    float*  lpart = hbuf  + 2097152;          // [32][1024] fp32
    float*  linvs = lpart + 32768;            // [1024][32] fp32
    ushort* AMw   = (ushort*)(linvs + 32768); // [1024][32][2048] bf16 k-permuted

    dim3 blk(256);
    // fused converts + weight transposes + lpart clear
    prep<<<9248, blk, 0, stream>>>(memory, x, pos_emb, Wq, Wkv, Wrel, Wo,
                                   cb, pb, Wqt, Wkvt, Wrelt, Wot, lpart);
    // all projections: 256^2 tiles, 8 waves, vectorized VtB epilogue
    proj_all<<<224, dim3(512), 0, stream>>>(cb, pb, Wqt, Wkvt, Wrelt, bu, bv,
                                            quB, qvB, kbB, VtB, rbB);
    // scores -> planes (block-coop LDS staging, counted vmcnt, raw barriers)
    attn_score<<<dim3(2720), blk, 0, stream>>>(quB, qvB, kbB, rbB, lpart, AMw);
    // PV as causal-K GEMM with register-prefetch pipeline; folds o_combine
    pv_gemm<<<dim3(512), blk, 0, stream>>>(AMw, VtB, lpart, OvecB, linvs);
    // fused output projection (reg-prefetch pipeline) + attn_matrix reduction
    tail_fused<<<dim3(1536), blk, 0, stream>>>(OvecB, Wot, x, hbuf,
                                               AMw, linvs, AM);
    // layernorm
    ln_kernel<<<2048, blk, 0, stream>>>(hbuf, gamma, beta, out);
}